// Round 6
// baseline (429.464 us; speedup 1.0000x reference)
//
#include <hip/hip_runtime.h>
#include <cstdint>
#include <cstddef>

// Problem constants
constexpr int B_   = 4;
constexpr int SEQ  = 2048;
constexpr int E    = 1024;   // embed dim
constexpr int KVE  = 512;    // kv embed dim
constexpr int H    = 4;      // kv heads
constexpr int ROWS = B_ * SEQ;   // 8192 tokens

typedef short short8   __attribute__((ext_vector_type(8)));
typedef short short4v  __attribute__((ext_vector_type(4)));
typedef float floatx4  __attribute__((ext_vector_type(4)));
typedef float floatx16 __attribute__((ext_vector_type(16)));

__device__ inline short f2bf(float f) {   // RNE float->bf16
    uint32_t u = __builtin_bit_cast(uint32_t, f);
    u = (u + 0x7fff + ((u >> 16) & 1)) >> 16;
    return (short)u;
}
__device__ inline float bf2f(short s) {
    return __builtin_bit_cast(float, (uint32_t)(uint16_t)s << 16);
}
__device__ inline void gl_lds16(const void* g, void* l) {
    __builtin_amdgcn_global_load_lds(
        (const __attribute__((address_space(1))) unsigned int*)g,
        (__attribute__((address_space(3))) unsigned int*)l, 16, 0, 0);
}

// ---------------------------------------------------------------------------
// Fused preprocessing: weight stats -> (release) -> activation quant ->
// (acquire spin) -> weight ternary quant.  Grid MUST be 1024 blocks
// (co-resident: 4 blocks/CU, tiny LDS, low VGPR) for the spin to be safe.
// ---------------------------------------------------------------------------
__global__ __launch_bounds__(256) void fused_pre(
    const float* __restrict__ qx, const float* __restrict__ kx,
    const float* __restrict__ vx,
    const float* __restrict__ w0, const float* __restrict__ w1,
    const float* __restrict__ w2, const float* __restrict__ w3,
    short* __restrict__ xq01, short* __restrict__ xq2,
    float* __restrict__ dqv,
    short* __restrict__ o0, short* __restrict__ o1,
    short* __restrict__ o2, short* __restrict__ o3,
    float* __restrict__ stats, int* __restrict__ counter)
{
    __shared__ float red1[4], red2[4];
    __shared__ float evals[4];
    int tid = threadIdx.x, bid = blockIdx.x;
    int lane = tid & 63, wv = tid >> 6;
    const float* wp[4] = { w0, w1, w2, w3 };
    short* op[4] = { o0, o1, o2, o3 };
    const int wn[4] = { 1024 * 1024, 512 * 1024, 512 * 1024, 512 * 1024 };

    // ---- phase A1: weight stat partials -> atomicAdd into stats
    for (int m = 0; m < 4; m++) {
        int n4 = wn[m] >> 2;
        float s = 0.f, sa = 0.f;
        for (int i = bid * 256 + tid; i < n4; i += 1024 * 256) {
            float4 x = ((const float4*)wp[m])[i];
            s += x.x + x.y + x.z + x.w;
            sa += fabsf(x.x) + fabsf(x.y) + fabsf(x.z) + fabsf(x.w);
        }
#pragma unroll
        for (int o = 32; o; o >>= 1) { s += __shfl_xor(s, o); sa += __shfl_xor(sa, o); }
        if (!lane) { red1[wv] = s; red2[wv] = sa; }
        __syncthreads();
        if (!tid) {
            atomicAdd(&stats[2 * m],     red1[0] + red1[1] + red1[2] + red1[3]);
            atomicAdd(&stats[2 * m + 1], red2[0] + red2[1] + red2[2] + red2[3]);
        }
        __syncthreads();
    }
    if (!tid)
        __hip_atomic_fetch_add(counter, 1, __ATOMIC_RELEASE, __HIP_MEMORY_SCOPE_AGENT);

    // ---- phase A2: activation RMSNorm + int8 quant (exact bf16), grid-stride
    for (int rowi = bid; rowi < 3 * ROWS; rowi += 1024) {
        int z = rowi >> 13, r = rowi & (ROWS - 1);
        const float* x = (z == 0) ? qx : (z == 1) ? kx : vx;
        short* xq = (z == 2) ? xq2 : xq01 + (size_t)z * ROWS * E;
        size_t base = (size_t)r * E;
        float4 t = *(const float4*)(x + base + tid * 4);
        float v[4] = { t.x, t.y, t.z, t.w };
        float ss = 0.f, am = 0.f;
#pragma unroll
        for (int i = 0; i < 4; i++) { ss += v[i] * v[i]; am = fmaxf(am, fabsf(v[i])); }
#pragma unroll
        for (int o = 32; o; o >>= 1) { ss += __shfl_xor(ss, o); am = fmaxf(am, __shfl_xor(am, o)); }
        if (!lane) { red1[wv] = ss; red2[wv] = am; }
        __syncthreads();
        ss = red1[0] + red1[1] + red1[2] + red1[3];
        am = fmaxf(fmaxf(red2[0], red2[1]), fmaxf(red2[2], red2[3]));
        float rms = rsqrtf(ss * (1.0f / E) + 1e-6f);
        float cl  = fmaxf(am * rms, 1e-5f);
        float kf  = rms * (127.0f / cl);
        short4v pk;
#pragma unroll
        for (int i = 0; i < 4; i++) {
            int qi = (int)rintf(v[i] * kf);
            qi = max(-128, min(127, qi));
            pk[i] = f2bf((float)qi);
        }
        *(short4v*)(xq + base + tid * 4) = pk;
        if (!tid) dqv[(size_t)z * ROWS + r] = cl * (1.0f / 127.0f);
        __syncthreads();   // protect red1/red2 reuse
    }

    // ---- phase B: wait for all stat partials, then ternary weight quant
    if (!tid) {
        while (__hip_atomic_load(counter, __ATOMIC_ACQUIRE, __HIP_MEMORY_SCOPE_AGENT)
               < (int)gridDim.x) {}
#pragma unroll
        for (int m = 0; m < 4; m++)
            evals[m] = __hip_atomic_load(&stats[2 * m], __ATOMIC_RELAXED,
                                         __HIP_MEMORY_SCOPE_AGENT) / (float)wn[m];
    }
    __syncthreads();
    for (int m = 0; m < 4; m++) {
        float e = evals[m];
        int n4 = wn[m] >> 2;
        for (int i = bid * 256 + tid; i < n4; i += 1024 * 256) {
            float4 x = ((const float4*)wp[m])[i];
            short4v q;
            q.x = (x.x > e) ? (short)0x3F80 : (x.x < e) ? (short)0xBF80 : (short)0;
            q.y = (x.y > e) ? (short)0x3F80 : (x.y < e) ? (short)0xBF80 : (short)0;
            q.z = (x.z > e) ? (short)0x3F80 : (x.z < e) ? (short)0xBF80 : (short)0;
            q.w = (x.w > e) ? (short)0x3F80 : (x.w < e) ? (short)0xBF80 : (short)0;
            *(short4v*)(op[m] + ((size_t)i << 2)) = q;
        }
    }
}

// ---------------------------------------------------------------------------
// bf16 MFMA GEMM body (bit-exact). 128x128 tile, BK=32, global_load_lds w16.
// ---------------------------------------------------------------------------
template <bool F32OUT>
__device__ inline void gemm_body(
    const short* __restrict__ A, const short* __restrict__ W,
    const float* __restrict__ dqv, float sw, void* __restrict__ Cout,
    int O, int K, short* As, short* Ws, size_t row0, size_t c0)
{
    int tid = threadIdx.x;
    int w = tid >> 6, lane = tid & 63;
    int quad = lane >> 4, l15 = lane & 15;
    int mbase = (w & 1) * 64, nbase = (w >> 1) * 64;

    floatx4 acc[4][4];
#pragma unroll
    for (int i = 0; i < 4; i++)
#pragma unroll
        for (int j = 0; j < 4; j++) acc[i][j] = (floatx4){0.f, 0.f, 0.f, 0.f};

    int cA0 = tid, cA1 = tid + 256;
    int rA0 = cA0 >> 2, gA0 = (cA0 & 3) ^ (rA0 & 3);
    int rA1 = cA1 >> 2, gA1 = (cA1 & 3) ^ (rA1 & 3);
    const short* Ag0 = A + (row0 + rA0) * K + gA0 * 8;
    const short* Ag1 = A + (row0 + rA1) * K + gA1 * 8;
    const short* Wg0 = W + (c0 + rA0) * K + gA0 * 8;
    const short* Wg1 = W + (c0 + rA1) * K + gA1 * 8;
    short* lA0 = As + cA0 * 8;  short* lA1 = As + cA1 * 8;
    short* lW0 = Ws + cA0 * 8;  short* lW1 = Ws + cA1 * 8;

    for (int kt = 0; kt < K; kt += 32) {
        __syncthreads();
        gl_lds16(Ag0 + kt, lA0);
        gl_lds16(Ag1 + kt, lA1);
        gl_lds16(Wg0 + kt, lW0);
        gl_lds16(Wg1 + kt, lW1);
        __syncthreads();
        short8 af[4], bfr[4];
#pragma unroll
        for (int mt = 0; mt < 4; mt++) {
            int row = mbase + mt * 16 + l15;
            int pos = quad ^ (row & 3);
            af[mt] = *(const short8*)(As + row * 32 + pos * 8);
        }
#pragma unroll
        for (int nt = 0; nt < 4; nt++) {
            int row = nbase + nt * 16 + l15;
            int pos = quad ^ (row & 3);
            bfr[nt] = *(const short8*)(Ws + row * 32 + pos * 8);
        }
#pragma unroll
        for (int mt = 0; mt < 4; mt++)
#pragma unroll
            for (int nt = 0; nt < 4; nt++)
                acc[mt][nt] = __builtin_amdgcn_mfma_f32_16x16x32_bf16(
                    af[mt], bfr[nt], acc[mt][nt], 0, 0, 0);
    }

#pragma unroll
    for (int mt = 0; mt < 4; mt++) {
#pragma unroll
        for (int r = 0; r < 4; r++) {
            size_t grow = row0 + mbase + mt * 16 + quad * 4 + r;
            float scv = sw * dqv[grow];
#pragma unroll
            for (int nt = 0; nt < 4; nt++) {
                size_t gcol = c0 + nbase + nt * 16 + l15;
                float v = acc[mt][nt][r] * scv;
                if constexpr (F32OUT) ((float*)Cout)[grow * O + gcol] = v;
                else                  ((short*)Cout)[grow * O + gcol] = f2bf(v);
            }
        }
    }
}

// Batched QKV GEMM: flat 1024-block grid (512 q / 256 k / 256 v tiles).
__global__ __launch_bounds__(256) void gemm_qkv(
    const short* __restrict__ xq01, const short* __restrict__ xq2,
    const short* __restrict__ wq_q, const short* __restrict__ wq_k,
    const short* __restrict__ wq_v, const float* __restrict__ dqv,
    const float* __restrict__ stats,
    short* __restrict__ qb, short* __restrict__ kb, short* __restrict__ vb)
{
    __shared__ short As[128 * 32];
    __shared__ short Ws[128 * 32];
    int id = blockIdx.x;
    int z, bx, by;
    if (id < 512)      { z = 0; bx = id & 7; by = id >> 3; }
    else if (id < 768) { z = 1; int t = id - 512; bx = t & 3; by = t >> 2; }
    else               { z = 2; int t = id - 768; bx = t & 3; by = t >> 2; }
    int O = z ? KVE : E;
    const short* A = (z == 0) ? xq01 : (z == 1) ? xq01 + (size_t)ROWS * E : xq2;
    const short* W = (z == 0) ? wq_q : (z == 1) ? wq_k : wq_v;
    short* outp = (z == 0) ? qb : (z == 1) ? kb : vb;
    float sw = stats[2 * z + 1] / (float)(O * E);
    gemm_body<false>(A, W, dqv + (size_t)z * ROWS, sw, outp, O, E, As, Ws,
                     (size_t)by * 128, (size_t)bx * 128);
}

// Output GEMM (fp32 out, K=512)
__global__ __launch_bounds__(256) void gemm_out(
    const short* __restrict__ A, const short* __restrict__ W,
    const float* __restrict__ dqv, const float* __restrict__ stats,
    float* __restrict__ Cout)
{
    __shared__ short As[128 * 32];
    __shared__ short Ws[128 * 32];
    float sw = stats[7] / (float)(E * KVE);
    gemm_body<true>(A, W, dqv, sw, Cout, E, KVE, As, Ws,
                    (size_t)blockIdx.y * 128, (size_t)blockIdx.x * 128);
}

// ---------------------------------------------------------------------------
// MFMA flash attention v5: 32x32x16 MFMA (half the LDS bytes per MAC),
// S^T orientation, per-lane scalar softmax (1 shuffle), Q frags from global.
// Block: 128 q-rows x head x KV-half. Wave owns 32 q-cols. Grid (64, H, 2).
// A-layout: A[m=lane&31][k=(lane>>5)*8+i]; C/D: col=lane&31,
// row=(reg&3)+8*(reg>>2)+4*(lane>>5)  [m74/m101 verified].
// ---------------------------------------------------------------------------
__global__ __launch_bounds__(256, 2) void attn_mfma(
    const short* __restrict__ qb, const short* __restrict__ kb,
    const short* __restrict__ vb, float* __restrict__ opart,
    float* __restrict__ mlbuf)
{
    __shared__ short Ks[64][132];
    __shared__ short Vt[128][68];
    __shared__ short Ps[128][68];
    int tid = threadIdx.x;
    int w = tid >> 6, lane = tid & 63;
    int l31 = lane & 31, hi = lane >> 5;
    int blk = blockIdx.x, h = blockIdx.y, half = blockIdx.z;
    int b = blk >> 4;                       // 16 q-tiles of 128 per batch
    size_t qrow0 = (size_t)blk * 128;
    size_t sbase = (size_t)b * SEQ + (size_t)half * (SEQ / 2);

    int sK = tid >> 2, cK = tid & 3;          // K staging: row, 32-col chunk
    int sV = (tid & 15) * 4, dV = tid >> 4;   // V staging: 4 rows, 8-col chunk

    // ---- prefetch KV tile 0 into registers
    short8 kreg[4], vreg[4];
    {
        const short* ksrc = kb + (sbase + sK) * KVE + h * 128 + cK * 32;
#pragma unroll
        for (int j = 0; j < 4; j++) kreg[j] = *(const short8*)(ksrc + j * 8);
        const short* vsrc = vb + (sbase + sV) * KVE + h * 128 + dV * 8;
#pragma unroll
        for (int j = 0; j < 4; j++) vreg[j] = *(const short8*)(vsrc + j * KVE);
    }

    // ---- Q^T B-frags straight from global: head-pair sum, fold 1/128
    short8 qfrag[8];
    {
        const short* src = qb + (qrow0 + w * 32 + l31) * E + h * 256 + hi * 8;
#pragma unroll
        for (int j = 0; j < 8; j++) {
            short8 a  = *(const short8*)(src + j * 16);
            short8 b2 = *(const short8*)(src + j * 16 + 128);
            short8 o;
#pragma unroll
            for (int e = 0; e < 8; e++)
                o[e] = f2bf((bf2f(a[e]) + bf2f(b2[e])) * (1.0f / 128.0f));
            qfrag[j] = o;
        }
    }

    floatx16 oacc[4];
#pragma unroll
    for (int dt = 0; dt < 4; dt++)
#pragma unroll
        for (int r = 0; r < 16; r++) oacc[dt][r] = 0.f;
    float m_s = -1e30f, l_s = 0.f;

    for (int st = 0; st < SEQ / 128; st++) {
        __syncthreads();   // prior readers of Ks/Vt done
        // commit prefetched K tile
#pragma unroll
        for (int j = 0; j < 4; j++)
            *(short8*)&Ks[sK][cK * 32 + j * 8] = kreg[j];
        // commit prefetched V tile (transposed)
#pragma unroll
        for (int i = 0; i < 8; i++) {
            short4v vv = { vreg[0][i], vreg[1][i], vreg[2][i], vreg[3][i] };
            *(short4v*)&Vt[dV * 8 + i][sV] = vv;
        }
        // issue next tile's global loads
        if (st + 1 < SEQ / 128) {
            size_t srow0 = sbase + (size_t)(st + 1) * 64;
            const short* ksrc = kb + (srow0 + sK) * KVE + h * 128 + cK * 32;
#pragma unroll
            for (int j = 0; j < 4; j++) kreg[j] = *(const short8*)(ksrc + j * 8);
            const short* vsrc = vb + (srow0 + sV) * KVE + h * 128 + dV * 8;
#pragma unroll
            for (int j = 0; j < 4; j++) vreg[j] = *(const short8*)(vsrc + j * KVE);
        }
        __syncthreads();
        // S^T = K * Q^T: two 32x32 tiles (keys 0-31, 32-63) x 32 q-cols
        floatx16 sc0, sc1;
#pragma unroll
        for (int r = 0; r < 16; r++) { sc0[r] = 0.f; sc1[r] = 0.f; }
#pragma unroll
        for (int j = 0; j < 8; j++) {
            short8 kf0 = *(const short8*)&Ks[l31][j * 16 + hi * 8];
            short8 kf1 = *(const short8*)&Ks[32 + l31][j * 16 + hi * 8];
            sc0 = __builtin_amdgcn_mfma_f32_32x32x16_bf16(kf0, qfrag[j], sc0, 0, 0, 0);
            sc1 = __builtin_amdgcn_mfma_f32_32x32x16_bf16(kf1, qfrag[j], sc1, 0, 0, 0);
        }
        // online softmax: lane + lane^32 together hold all 64 keys for this q
        float mx = sc0[0];
#pragma unroll
        for (int r = 0; r < 16; r++) { mx = fmaxf(mx, sc0[r]); mx = fmaxf(mx, sc1[r]); }
        mx = fmaxf(mx, __shfl_xor(mx, 32));
        float nm = fmaxf(m_s, mx);
        float alpha = __expf(m_s - nm);
        m_s = nm;
        float rs = 0.f;
#pragma unroll
        for (int r = 0; r < 16; r++) {
            float p0 = __expf(sc0[r] - nm); sc0[r] = p0; rs += p0;
            float p1 = __expf(sc1[r] - nm); sc1[r] = p1; rs += p1;
        }
        rs += __shfl_xor(rs, 32);
        l_s = l_s * alpha + rs;
        // P -> LDS: regs c*4..c*4+3 are consecutive keys 8c+4hi(+t*32)
        int qrow = w * 32 + l31;
#pragma unroll
        for (int c = 0; c < 4; c++) {
            short4v p0 = { f2bf(sc0[c * 4]), f2bf(sc0[c * 4 + 1]),
                           f2bf(sc0[c * 4 + 2]), f2bf(sc0[c * 4 + 3]) };
            *(short4v*)&Ps[qrow][c * 8 + hi * 4] = p0;
            short4v p1 = { f2bf(sc1[c * 4]), f2bf(sc1[c * 4 + 1]),
                           f2bf(sc1[c * 4 + 2]), f2bf(sc1[c * 4 + 3]) };
            *(short4v*)&Ps[qrow][32 + c * 8 + hi * 4] = p1;
        }
        // rescale O^T
#pragma unroll
        for (int dt = 0; dt < 4; dt++)
#pragma unroll
            for (int r = 0; r < 16; r++) oacc[dt][r] *= alpha;
        // PV: O^T = V^T * P^T (A = Vt frag, B = P^T frag; same-wave LDS RAW)
        short8 pb[4];
#pragma unroll
        for (int j = 0; j < 4; j++)
            pb[j] = *(const short8*)&Ps[qrow][j * 16 + hi * 8];
#pragma unroll
        for (int dt = 0; dt < 4; dt++)
#pragma unroll
            for (int j = 0; j < 4; j++) {
                short8 vf = *(const short8*)&Vt[dt * 32 + l31][j * 16 + hi * 8];
                oacc[dt] = __builtin_amdgcn_mfma_f32_32x32x16_bf16(vf, pb[j], oacc[dt], 0, 0, 0);
            }
    }
    // epilogue: normalized partial O + (m,l)
    {
        float inv = 1.0f / l_s;
        size_t grow = qrow0 + w * 32 + l31;
        float* dst = opart + ((size_t)half * ROWS + grow) * KVE + h * 128;
#pragma unroll
        for (int dt = 0; dt < 4; dt++)
#pragma unroll
            for (int c = 0; c < 4; c++) {
                float4 o4 = { oacc[dt][c * 4] * inv, oacc[dt][c * 4 + 1] * inv,
                              oacc[dt][c * 4 + 2] * inv, oacc[dt][c * 4 + 3] * inv };
                *(float4*)(dst + dt * 32 + c * 8 + hi * 4) = o4;
            }
        if (hi == 0) {
            float* ml = mlbuf + (((size_t)half * ROWS + grow) * H + h) * 2;
            ml[0] = m_s;
            ml[1] = l_s;
        }
    }
}

// ---------------------------------------------------------------------------
// Partial combine + LayerNorm + RMSNorm + int8 quant (exact bf16 out)
// ---------------------------------------------------------------------------
__global__ __launch_bounds__(256) void ln_combine_kernel(
    const float* __restrict__ opart, const float* __restrict__ mlbuf,
    const float* __restrict__ gamma, const float* __restrict__ beta,
    short* __restrict__ xq, float* __restrict__ dqv)
{
    int row = blockIdx.x, tid = threadIdx.x;
    int h = tid >> 6;
    const float* ml0 = mlbuf + ((size_t)row * H + h) * 2;
    const float* ml1 = mlbuf + (((size_t)ROWS + row) * H + h) * 2;
    float m1 = ml0[0], l1v = ml0[1], m2 = ml1[0], l2v = ml1[1];
    float M = fmaxf(m1, m2);
    float w1 = l1v * __expf(m1 - M), w2 = l2v * __expf(m2 - M);
    float winv = 1.0f / (w1 + w2);
    w1 *= winv; w2 *= winv;
    float2 o1 = *(const float2*)(opart + (size_t)row * KVE + tid * 2);
    float2 o2 = *(const float2*)(opart + ((size_t)ROWS + row) * KVE + tid * 2);
    float vx = o1.x * w1 + o2.x * w2;
    float vy = o1.y * w1 + o2.y * w2;

    float s = vx + vy, ss = vx * vx + vy * vy;
#pragma unroll
    for (int o = 32; o; o >>= 1) { s += __shfl_xor(s, o); ss += __shfl_xor(ss, o); }
    __shared__ float r1[4], r2[4];
    int lane = tid & 63, wv = tid >> 6;
    if (!lane) { r1[wv] = s; r2[wv] = ss; }
    __syncthreads();
    float stot = r1[0] + r1[1] + r1[2] + r1[3];
    float sstot = r2[0] + r2[1] + r2[2] + r2[3];
    float mu = stot * (1.0f / KVE);
    float var = fmaxf(sstot * (1.0f / KVE) - mu * mu, 0.0f);
    float inv = rsqrtf(var + 1e-5f);
    float2 g = *(const float2*)(gamma + tid * 2);
    float2 be = *(const float2*)(beta + tid * 2);
    float y0 = (vx - mu) * inv * g.x + be.x;
    float y1 = (vy - mu) * inv * g.y + be.y;
    float sy = y0 * y0 + y1 * y1;
    float am = fmaxf(fabsf(y0), fabsf(y1));
#pragma unroll
    for (int o = 32; o; o >>= 1) { sy += __shfl_xor(sy, o); am = fmaxf(am, __shfl_xor(am, o)); }
    __syncthreads();
    if (!lane) { r1[wv] = sy; r2[wv] = am; }
    __syncthreads();
    float sytot = r1[0] + r1[1] + r1[2] + r1[3];
    float amax = fmaxf(fmaxf(r2[0], r2[1]), fmaxf(r2[2], r2[3]));
    float rms = rsqrtf(sytot * (1.0f / KVE) + 1e-6f);
    float cl = fmaxf(amax * rms, 1e-5f);
    float kf = rms * (127.0f / cl);
    int q0 = max(-128, min(127, (int)rintf(y0 * kf)));
    int q1 = max(-128, min(127, (int)rintf(y1 * kf)));
    xq[(size_t)row * KVE + tid * 2]     = f2bf((float)q0);
    xq[(size_t)row * KVE + tid * 2 + 1] = f2bf((float)q1);
    if (!tid) dqv[row] = cl * (1.0f / 127.0f);
}

// ---------------------------------------------------------------------------
extern "C" void kernel_launch(void* const* d_in, const int* in_sizes, int n_in,
                              void* d_out, int out_size, void* d_ws, size_t ws_size,
                              hipStream_t stream)
{
    const float* query = (const float*)d_in[0];
    const float* key   = (const float*)d_in[1];
    const float* value = (const float*)d_in[2];
    const float* q_w   = (const float*)d_in[3];
    const float* k_w   = (const float*)d_in[4];
    const float* v_w   = (const float*)d_in[5];
    const float* out_w = (const float*)d_in[6];
    const float* ln_g  = (const float*)d_in[7];
    const float* ln_b  = (const float*)d_in[8];
    float* out = (float*)d_out;

    // workspace carve (xq slice 2 aliases opart: dead before attn writes it)
    char* p = (char*)d_ws;
    float* stats   = (float*)p;
    int*   counter = (int*)(p + 64);
    p += 256;
    short* wq_q = (short*)p;   p += (size_t)1024 * 1024 * 2;
    short* wq_k = (short*)p;   p += (size_t)512 * 1024 * 2;
    short* wq_v = (short*)p;   p += (size_t)512 * 1024 * 2;
    short* wq_o = (short*)p;   p += (size_t)1024 * 512 * 2;
    short* xq01 = (short*)p;   p += (size_t)2 * ROWS * E * 2;
    float* dqv  = (float*)p;   p += (size_t)3 * ROWS * 4;
    short* qb   = (short*)p;   p += (size_t)ROWS * E * 2;
    short* kb   = (short*)p;   p += (size_t)ROWS * KVE * 2;
    short* vb   = (short*)p;   p += (size_t)ROWS * KVE * 2;
    float* opart = (float*)p;  p += (size_t)2 * ROWS * KVE * 4;
    float* mlbuf = (float*)p;  p += (size_t)2 * ROWS * H * 2 * 4;
    short* xq2  = (short*)opart;  // alias: dead before attn runs
    if ((size_t)(p - (char*)d_ws) > ws_size) return;

    dim3 blk(256);
    hipMemsetAsync(stats, 0, 256, stream);   // zeroes stats + counter

    fused_pre<<<dim3(1024), blk, 0, stream>>>(query, key, value,
        q_w, k_w, v_w, out_w, xq01, xq2, dqv, wq_q, wq_k, wq_v, wq_o,
        stats, counter);

    gemm_qkv<<<dim3(1024), blk, 0, stream>>>(xq01, xq2, wq_q, wq_k, wq_v,
        dqv, stats, qb, kb, vb);

    attn_mfma<<<dim3(ROWS / 128, H, 2), blk, 0, stream>>>(qb, kb, vb, opart, mlbuf);

    ln_combine_kernel<<<ROWS, blk, 0, stream>>>(opart, mlbuf, ln_g, ln_b, xq01, dqv);
    gemm_out<<<dim3(8, 64), blk, 0, stream>>>(xq01, wq_o, dqv, stats, out);
}

// Round 7
// 331.897 us; speedup vs baseline: 1.2940x; 1.2940x over previous
//
#include <hip/hip_runtime.h>
#include <cstdint>
#include <cstddef>

// Problem constants
constexpr int B_   = 4;
constexpr int SEQ  = 2048;
constexpr int E    = 1024;   // embed dim
constexpr int KVE  = 512;    // kv embed dim
constexpr int H    = 4;      // kv heads
constexpr int ROWS = B_ * SEQ;   // 8192 tokens

typedef short short8   __attribute__((ext_vector_type(8)));
typedef short short4v  __attribute__((ext_vector_type(4)));
typedef float floatx4  __attribute__((ext_vector_type(4)));
typedef float floatx16 __attribute__((ext_vector_type(16)));

__device__ inline short f2bf(float f) {   // RNE float->bf16
    uint32_t u = __builtin_bit_cast(uint32_t, f);
    u = (u + 0x7fff + ((u >> 16) & 1)) >> 16;
    return (short)u;
}
__device__ inline float bf2f(short s) {
    return __builtin_bit_cast(float, (uint32_t)(uint16_t)s << 16);
}
__device__ inline void gl_lds16(const void* g, void* l) {
    __builtin_amdgcn_global_load_lds(
        (const __attribute__((address_space(1))) unsigned int*)g,
        (__attribute__((address_space(3))) unsigned int*)l, 16, 0, 0);
}

// ---------------------------------------------------------------------------
// Weight stats: per-matrix sum(w) and sum(|w|)
// ---------------------------------------------------------------------------
__global__ __launch_bounds__(256) void wstats_kernel(
    const float* __restrict__ w0, const float* __restrict__ w1,
    const float* __restrict__ w2, const float* __restrict__ w3,
    int n0, int n1, int n2, int n3, float* __restrict__ stats)
{
    int m = blockIdx.y;
    const float* w = (m == 0) ? w0 : (m == 1) ? w1 : (m == 2) ? w2 : w3;
    int n = (m == 0) ? n0 : (m == 1) ? n1 : (m == 2) ? n2 : n3;
    float s = 0.f, sa = 0.f;
    for (int i = blockIdx.x * 256 + threadIdx.x; i < n; i += gridDim.x * 256) {
        float x = w[i];
        s += x; sa += fabsf(x);
    }
#pragma unroll
    for (int o = 32; o; o >>= 1) { s += __shfl_xor(s, o); sa += __shfl_xor(sa, o); }
    __shared__ float ls[4], lsa[4];
    int lane = threadIdx.x & 63, wv = threadIdx.x >> 6;
    if (!lane) { ls[wv] = s; lsa[wv] = sa; }
    __syncthreads();
    if (!threadIdx.x) {
        atomicAdd(&stats[2 * m],     ls[0] + ls[1] + ls[2] + ls[3]);
        atomicAdd(&stats[2 * m + 1], lsa[0] + lsa[1] + lsa[2] + lsa[3]);
    }
}

// ---------------------------------------------------------------------------
// Weight ternary quant -> bf16 {-1,0,+1}
// ---------------------------------------------------------------------------
__global__ __launch_bounds__(256) void wquant_kernel(
    const float* __restrict__ w0, const float* __restrict__ w1,
    const float* __restrict__ w2, const float* __restrict__ w3,
    int n0, int n1, int n2, int n3, const float* __restrict__ stats,
    short* __restrict__ o0, short* __restrict__ o1,
    short* __restrict__ o2, short* __restrict__ o3)
{
    int m = blockIdx.y;
    const float* w = (m == 0) ? w0 : (m == 1) ? w1 : (m == 2) ? w2 : w3;
    int n = (m == 0) ? n0 : (m == 1) ? n1 : (m == 2) ? n2 : n3;
    short* o = (m == 0) ? o0 : (m == 1) ? o1 : (m == 2) ? o2 : o3;
    float e = stats[2 * m] / (float)n;
    int n4 = n >> 2;
    for (int i = blockIdx.x * 256 + threadIdx.x; i < n4; i += gridDim.x * 256) {
        float4 x = ((const float4*)w)[i];
        short4v q;
        q.x = (x.x > e) ? (short)0x3F80 : (x.x < e) ? (short)0xBF80 : (short)0;
        q.y = (x.y > e) ? (short)0x3F80 : (x.y < e) ? (short)0xBF80 : (short)0;
        q.z = (x.z > e) ? (short)0x3F80 : (x.z < e) ? (short)0xBF80 : (short)0;
        q.w = (x.w > e) ? (short)0x3F80 : (x.w < e) ? (short)0xBF80 : (short)0;
        *(short4v*)(o + ((size_t)i << 2)) = q;
    }
}

// ---------------------------------------------------------------------------
// Activation quant, wave-per-row (no barriers): RMSNorm -> int8 as exact bf16
// Block = 4 waves = 4 rows. Grid 3*ROWS/4. Lane owns cols lane*4 + j*256.
// ---------------------------------------------------------------------------
__global__ __launch_bounds__(256) void aquant3_kernel(
    const float* __restrict__ q, const float* __restrict__ k,
    const float* __restrict__ vv, short* __restrict__ xq01,
    short* __restrict__ xq2, float* __restrict__ dqv)
{
    int lane = threadIdx.x & 63, wv = threadIdx.x >> 6;
    int rowi = blockIdx.x * 4 + wv;
    int z = rowi >> 13, r = rowi & (ROWS - 1);
    const float* x = (z == 0) ? q : (z == 1) ? k : vv;
    short* xq = (z == 2) ? xq2 : xq01 + (size_t)z * ROWS * E;
    size_t base = (size_t)r * E;
    float4 v[4];
    float ss = 0.f, am = 0.f;
#pragma unroll
    for (int j = 0; j < 4; j++) {
        v[j] = *(const float4*)(x + base + lane * 4 + j * 256);
        ss += v[j].x * v[j].x + v[j].y * v[j].y + v[j].z * v[j].z + v[j].w * v[j].w;
        am = fmaxf(am, fmaxf(fmaxf(fabsf(v[j].x), fabsf(v[j].y)),
                             fmaxf(fabsf(v[j].z), fabsf(v[j].w))));
    }
#pragma unroll
    for (int o = 32; o; o >>= 1) { ss += __shfl_xor(ss, o); am = fmaxf(am, __shfl_xor(am, o)); }
    float rms = rsqrtf(ss * (1.0f / E) + 1e-6f);
    float cl  = fmaxf(am * rms, 1e-5f);
    float kf  = rms * (127.0f / cl);
#pragma unroll
    for (int j = 0; j < 4; j++) {
        short4v pk;
        pk.x = f2bf((float)max(-128, min(127, (int)rintf(v[j].x * kf))));
        pk.y = f2bf((float)max(-128, min(127, (int)rintf(v[j].y * kf))));
        pk.z = f2bf((float)max(-128, min(127, (int)rintf(v[j].z * kf))));
        pk.w = f2bf((float)max(-128, min(127, (int)rintf(v[j].w * kf))));
        *(short4v*)(xq + base + lane * 4 + j * 256) = pk;
    }
    if (!lane) dqv[(size_t)z * ROWS + r] = cl * (1.0f / 127.0f);
}

// ---------------------------------------------------------------------------
// bf16 MFMA GEMM body (bit-exact). 128x128 tile, BK=32, global_load_lds w16.
// ---------------------------------------------------------------------------
template <bool F32OUT>
__device__ inline void gemm_body(
    const short* __restrict__ A, const short* __restrict__ W,
    const float* __restrict__ dqv, float sw, void* __restrict__ Cout,
    int O, int K, short* As, short* Ws, size_t row0, size_t c0)
{
    int tid = threadIdx.x;
    int w = tid >> 6, lane = tid & 63;
    int quad = lane >> 4, l15 = lane & 15;
    int mbase = (w & 1) * 64, nbase = (w >> 1) * 64;

    floatx4 acc[4][4];
#pragma unroll
    for (int i = 0; i < 4; i++)
#pragma unroll
        for (int j = 0; j < 4; j++) acc[i][j] = (floatx4){0.f, 0.f, 0.f, 0.f};

    int cA0 = tid, cA1 = tid + 256;
    int rA0 = cA0 >> 2, gA0 = (cA0 & 3) ^ (rA0 & 3);
    int rA1 = cA1 >> 2, gA1 = (cA1 & 3) ^ (rA1 & 3);
    const short* Ag0 = A + (row0 + rA0) * K + gA0 * 8;
    const short* Ag1 = A + (row0 + rA1) * K + gA1 * 8;
    const short* Wg0 = W + (c0 + rA0) * K + gA0 * 8;
    const short* Wg1 = W + (c0 + rA1) * K + gA1 * 8;
    short* lA0 = As + cA0 * 8;  short* lA1 = As + cA1 * 8;
    short* lW0 = Ws + cA0 * 8;  short* lW1 = Ws + cA1 * 8;

    for (int kt = 0; kt < K; kt += 32) {
        __syncthreads();
        gl_lds16(Ag0 + kt, lA0);
        gl_lds16(Ag1 + kt, lA1);
        gl_lds16(Wg0 + kt, lW0);
        gl_lds16(Wg1 + kt, lW1);
        __syncthreads();
        short8 af[4], bfr[4];
#pragma unroll
        for (int mt = 0; mt < 4; mt++) {
            int row = mbase + mt * 16 + l15;
            int pos = quad ^ (row & 3);
            af[mt] = *(const short8*)(As + row * 32 + pos * 8);
        }
#pragma unroll
        for (int nt = 0; nt < 4; nt++) {
            int row = nbase + nt * 16 + l15;
            int pos = quad ^ (row & 3);
            bfr[nt] = *(const short8*)(Ws + row * 32 + pos * 8);
        }
#pragma unroll
        for (int mt = 0; mt < 4; mt++)
#pragma unroll
            for (int nt = 0; nt < 4; nt++)
                acc[mt][nt] = __builtin_amdgcn_mfma_f32_16x16x32_bf16(
                    af[mt], bfr[nt], acc[mt][nt], 0, 0, 0);
    }

#pragma unroll
    for (int mt = 0; mt < 4; mt++) {
#pragma unroll
        for (int r = 0; r < 4; r++) {
            size_t grow = row0 + mbase + mt * 16 + quad * 4 + r;
            float scv = sw * dqv[grow];
#pragma unroll
            for (int nt = 0; nt < 4; nt++) {
                size_t gcol = c0 + nbase + nt * 16 + l15;
                float v = acc[mt][nt][r] * scv;
                if constexpr (F32OUT) ((float*)Cout)[grow * O + gcol] = v;
                else                  ((short*)Cout)[grow * O + gcol] = f2bf(v);
            }
        }
    }
}

// Batched QKV GEMM: flat 1024-block grid (512 q / 256 k / 256 v tiles).
__global__ __launch_bounds__(256) void gemm_qkv(
    const short* __restrict__ xq01, const short* __restrict__ xq2,
    const short* __restrict__ wq_q, const short* __restrict__ wq_k,
    const short* __restrict__ wq_v, const float* __restrict__ dqv,
    const float* __restrict__ stats,
    short* __restrict__ qb, short* __restrict__ kb, short* __restrict__ vb)
{
    __shared__ short As[128 * 32];
    __shared__ short Ws[128 * 32];
    int id = blockIdx.x;
    int z, bx, by;
    if (id < 512)      { z = 0; bx = id & 7; by = id >> 3; }
    else if (id < 768) { z = 1; int t = id - 512; bx = t & 3; by = t >> 2; }
    else               { z = 2; int t = id - 768; bx = t & 3; by = t >> 2; }
    int O = z ? KVE : E;
    const short* A = (z == 0) ? xq01 : (z == 1) ? xq01 + (size_t)ROWS * E : xq2;
    const short* W = (z == 0) ? wq_q : (z == 1) ? wq_k : wq_v;
    short* outp = (z == 0) ? qb : (z == 1) ? kb : vb;
    float sw = stats[2 * z + 1] / (float)(O * E);
    gemm_body<false>(A, W, dqv + (size_t)z * ROWS, sw, outp, O, E, As, Ws,
                     (size_t)by * 128, (size_t)bx * 128);
}

// Output GEMM (fp32 out, K=512)
__global__ __launch_bounds__(256) void gemm_out(
    const short* __restrict__ A, const short* __restrict__ W,
    const float* __restrict__ dqv, const float* __restrict__ stats,
    float* __restrict__ Cout)
{
    __shared__ short As[128 * 32];
    __shared__ short Ws[128 * 32];
    float sw = stats[7] / (float)(E * KVE);
    gemm_body<true>(A, W, dqv, sw, Cout, E, KVE, As, Ws,
                    (size_t)blockIdx.y * 128, (size_t)blockIdx.x * 128);
}

// ---------------------------------------------------------------------------
// MFMA flash attention v5: 32x32x16 MFMA (half the LDS bytes per MAC),
// S^T orientation, per-lane scalar softmax (1 shuffle), Q frags from global.
// Block: 128 q-rows x head x KV-half. Wave owns 32 q-cols. Grid (64, H, 2).
// [layouts HW-verified via R6's absmax pass]
// ---------------------------------------------------------------------------
__global__ __launch_bounds__(256, 2) void attn_mfma(
    const short* __restrict__ qb, const short* __restrict__ kb,
    const short* __restrict__ vb, float* __restrict__ opart,
    float* __restrict__ mlbuf)
{
    __shared__ short Ks[64][132];
    __shared__ short Vt[128][68];
    __shared__ short Ps[128][68];
    int tid = threadIdx.x;
    int w = tid >> 6, lane = tid & 63;
    int l31 = lane & 31, hi = lane >> 5;
    int blk = blockIdx.x, h = blockIdx.y, half = blockIdx.z;
    int b = blk >> 4;                       // 16 q-tiles of 128 per batch
    size_t qrow0 = (size_t)blk * 128;
    size_t sbase = (size_t)b * SEQ + (size_t)half * (SEQ / 2);

    int sK = tid >> 2, cK = tid & 3;          // K staging: row, 32-col chunk
    int sV = (tid & 15) * 4, dV = tid >> 4;   // V staging: 4 rows, 8-col chunk

    // ---- prefetch KV tile 0 into registers
    short8 kreg[4], vreg[4];
    {
        const short* ksrc = kb + (sbase + sK) * KVE + h * 128 + cK * 32;
#pragma unroll
        for (int j = 0; j < 4; j++) kreg[j] = *(const short8*)(ksrc + j * 8);
        const short* vsrc = vb + (sbase + sV) * KVE + h * 128 + dV * 8;
#pragma unroll
        for (int j = 0; j < 4; j++) vreg[j] = *(const short8*)(vsrc + j * KVE);
    }

    // ---- Q^T B-frags straight from global: head-pair sum, fold 1/128
    short8 qfrag[8];
    {
        const short* src = qb + (qrow0 + w * 32 + l31) * E + h * 256 + hi * 8;
#pragma unroll
        for (int j = 0; j < 8; j++) {
            short8 a  = *(const short8*)(src + j * 16);
            short8 b2 = *(const short8*)(src + j * 16 + 128);
            short8 o;
#pragma unroll
            for (int e = 0; e < 8; e++)
                o[e] = f2bf((bf2f(a[e]) + bf2f(b2[e])) * (1.0f / 128.0f));
            qfrag[j] = o;
        }
    }

    floatx16 oacc[4];
#pragma unroll
    for (int dt = 0; dt < 4; dt++)
#pragma unroll
        for (int r = 0; r < 16; r++) oacc[dt][r] = 0.f;
    float m_s = -1e30f, l_s = 0.f;

    for (int st = 0; st < SEQ / 128; st++) {
        __syncthreads();   // prior readers of Ks/Vt done
        // commit prefetched K tile
#pragma unroll
        for (int j = 0; j < 4; j++)
            *(short8*)&Ks[sK][cK * 32 + j * 8] = kreg[j];
        // commit prefetched V tile (transposed)
#pragma unroll
        for (int i = 0; i < 8; i++) {
            short4v vv = { vreg[0][i], vreg[1][i], vreg[2][i], vreg[3][i] };
            *(short4v*)&Vt[dV * 8 + i][sV] = vv;
        }
        // issue next tile's global loads
        if (st + 1 < SEQ / 128) {
            size_t srow0 = sbase + (size_t)(st + 1) * 64;
            const short* ksrc = kb + (srow0 + sK) * KVE + h * 128 + cK * 32;
#pragma unroll
            for (int j = 0; j < 4; j++) kreg[j] = *(const short8*)(ksrc + j * 8);
            const short* vsrc = vb + (srow0 + sV) * KVE + h * 128 + dV * 8;
#pragma unroll
            for (int j = 0; j < 4; j++) vreg[j] = *(const short8*)(vsrc + j * KVE);
        }
        __syncthreads();
        // S^T = K * Q^T: two 32x32 tiles (keys 0-31, 32-63) x 32 q-cols
        floatx16 sc0, sc1;
#pragma unroll
        for (int r = 0; r < 16; r++) { sc0[r] = 0.f; sc1[r] = 0.f; }
#pragma unroll
        for (int j = 0; j < 8; j++) {
            short8 kf0 = *(const short8*)&Ks[l31][j * 16 + hi * 8];
            short8 kf1 = *(const short8*)&Ks[32 + l31][j * 16 + hi * 8];
            sc0 = __builtin_amdgcn_mfma_f32_32x32x16_bf16(kf0, qfrag[j], sc0, 0, 0, 0);
            sc1 = __builtin_amdgcn_mfma_f32_32x32x16_bf16(kf1, qfrag[j], sc1, 0, 0, 0);
        }
        // online softmax: lane + lane^32 together hold all 64 keys for this q
        float mx = sc0[0];
#pragma unroll
        for (int r = 0; r < 16; r++) { mx = fmaxf(mx, sc0[r]); mx = fmaxf(mx, sc1[r]); }
        mx = fmaxf(mx, __shfl_xor(mx, 32));
        float nm = fmaxf(m_s, mx);
        float alpha = __expf(m_s - nm);
        m_s = nm;
        float rs = 0.f;
#pragma unroll
        for (int r = 0; r < 16; r++) {
            float p0 = __expf(sc0[r] - nm); sc0[r] = p0; rs += p0;
            float p1 = __expf(sc1[r] - nm); sc1[r] = p1; rs += p1;
        }
        rs += __shfl_xor(rs, 32);
        l_s = l_s * alpha + rs;
        // P -> LDS: regs c*4..c*4+3 are consecutive keys 8c+4hi(+t*32)
        int qrow = w * 32 + l31;
#pragma unroll
        for (int c = 0; c < 4; c++) {
            short4v p0 = { f2bf(sc0[c * 4]), f2bf(sc0[c * 4 + 1]),
                           f2bf(sc0[c * 4 + 2]), f2bf(sc0[c * 4 + 3]) };
            *(short4v*)&Ps[qrow][c * 8 + hi * 4] = p0;
            short4v p1 = { f2bf(sc1[c * 4]), f2bf(sc1[c * 4 + 1]),
                           f2bf(sc1[c * 4 + 2]), f2bf(sc1[c * 4 + 3]) };
            *(short4v*)&Ps[qrow][32 + c * 8 + hi * 4] = p1;
        }
        // rescale O^T
#pragma unroll
        for (int dt = 0; dt < 4; dt++)
#pragma unroll
            for (int r = 0; r < 16; r++) oacc[dt][r] *= alpha;
        // PV: O^T = V^T * P^T (A = Vt frag, B = P^T frag; same-wave LDS RAW)
        short8 pb[4];
#pragma unroll
        for (int j = 0; j < 4; j++)
            pb[j] = *(const short8*)&Ps[qrow][j * 16 + hi * 8];
#pragma unroll
        for (int dt = 0; dt < 4; dt++)
#pragma unroll
            for (int j = 0; j < 4; j++) {
                short8 vf = *(const short8*)&Vt[dt * 32 + l31][j * 16 + hi * 8];
                oacc[dt] = __builtin_amdgcn_mfma_f32_32x32x16_bf16(vf, pb[j], oacc[dt], 0, 0, 0);
            }
    }
    // epilogue: normalized partial O + (m,l)
    {
        float inv = 1.0f / l_s;
        size_t grow = qrow0 + w * 32 + l31;
        float* dst = opart + ((size_t)half * ROWS + grow) * KVE + h * 128;
#pragma unroll
        for (int dt = 0; dt < 4; dt++)
#pragma unroll
            for (int c = 0; c < 4; c++) {
                float4 o4 = { oacc[dt][c * 4] * inv, oacc[dt][c * 4 + 1] * inv,
                              oacc[dt][c * 4 + 2] * inv, oacc[dt][c * 4 + 3] * inv };
                *(float4*)(dst + dt * 32 + c * 8 + hi * 4) = o4;
            }
        if (hi == 0) {
            float* ml = mlbuf + (((size_t)half * ROWS + grow) * H + h) * 2;
            ml[0] = m_s;
            ml[1] = l_s;
        }
    }
}

// ---------------------------------------------------------------------------
// Partial combine + LayerNorm + RMSNorm + int8 quant, wave-per-row (no
// barriers). Block = 4 waves = 4 rows, grid ROWS/4. Lane owns cols
// lane*4 + j*256 (j=0,1); head h = j*2 + (lane>>5).
// ---------------------------------------------------------------------------
__global__ __launch_bounds__(256) void ln_combine_kernel(
    const float* __restrict__ opart, const float* __restrict__ mlbuf,
    const float* __restrict__ gamma, const float* __restrict__ beta,
    short* __restrict__ xq, float* __restrict__ dqv)
{
    int lane = threadIdx.x & 63, wv = threadIdx.x >> 6;
    int row = blockIdx.x * 4 + wv;
    float4 y[2];
    float s = 0.f, ss = 0.f;
#pragma unroll
    for (int j = 0; j < 2; j++) {
        int col = lane * 4 + j * 256;
        int h = j * 2 + (lane >> 5);
        const float* ml0 = mlbuf + ((size_t)row * H + h) * 2;
        const float* ml1 = mlbuf + (((size_t)ROWS + row) * H + h) * 2;
        float m1 = ml0[0], l1v = ml0[1], m2 = ml1[0], l2v = ml1[1];
        float M = fmaxf(m1, m2);
        float w1 = l1v * __expf(m1 - M), w2 = l2v * __expf(m2 - M);
        float winv = 1.0f / (w1 + w2);
        w1 *= winv; w2 *= winv;
        float4 o1 = *(const float4*)(opart + (size_t)row * KVE + col);
        float4 o2 = *(const float4*)(opart + ((size_t)ROWS + row) * KVE + col);
        float4 vv = { o1.x * w1 + o2.x * w2, o1.y * w1 + o2.y * w2,
                      o1.z * w1 + o2.z * w2, o1.w * w1 + o2.w * w2 };
        y[j] = vv;
        s += vv.x + vv.y + vv.z + vv.w;
        ss += vv.x * vv.x + vv.y * vv.y + vv.z * vv.z + vv.w * vv.w;
    }
#pragma unroll
    for (int o = 32; o; o >>= 1) { s += __shfl_xor(s, o); ss += __shfl_xor(ss, o); }
    float mu = s * (1.0f / KVE);
    float var = fmaxf(ss * (1.0f / KVE) - mu * mu, 0.0f);
    float inv = rsqrtf(var + 1e-5f);
    float sy = 0.f, am = 0.f;
#pragma unroll
    for (int j = 0; j < 2; j++) {
        int col = lane * 4 + j * 256;
        float4 g = *(const float4*)(gamma + col);
        float4 be = *(const float4*)(beta + col);
        y[j].x = (y[j].x - mu) * inv * g.x + be.x;
        y[j].y = (y[j].y - mu) * inv * g.y + be.y;
        y[j].z = (y[j].z - mu) * inv * g.z + be.z;
        y[j].w = (y[j].w - mu) * inv * g.w + be.w;
        sy += y[j].x * y[j].x + y[j].y * y[j].y + y[j].z * y[j].z + y[j].w * y[j].w;
        am = fmaxf(am, fmaxf(fmaxf(fabsf(y[j].x), fabsf(y[j].y)),
                             fmaxf(fabsf(y[j].z), fabsf(y[j].w))));
    }
#pragma unroll
    for (int o = 32; o; o >>= 1) { sy += __shfl_xor(sy, o); am = fmaxf(am, __shfl_xor(am, o)); }
    float rms = rsqrtf(sy * (1.0f / KVE) + 1e-6f);
    float cl = fmaxf(am * rms, 1e-5f);
    float kf = rms * (127.0f / cl);
#pragma unroll
    for (int j = 0; j < 2; j++) {
        int col = lane * 4 + j * 256;
        short4v pk;
        pk.x = f2bf((float)max(-128, min(127, (int)rintf(y[j].x * kf))));
        pk.y = f2bf((float)max(-128, min(127, (int)rintf(y[j].y * kf))));
        pk.z = f2bf((float)max(-128, min(127, (int)rintf(y[j].z * kf))));
        pk.w = f2bf((float)max(-128, min(127, (int)rintf(y[j].w * kf))));
        *(short4v*)(xq + (size_t)row * KVE + col) = pk;
    }
    if (!lane) dqv[row] = cl * (1.0f / 127.0f);
}

// ---------------------------------------------------------------------------
extern "C" void kernel_launch(void* const* d_in, const int* in_sizes, int n_in,
                              void* d_out, int out_size, void* d_ws, size_t ws_size,
                              hipStream_t stream)
{
    const float* query = (const float*)d_in[0];
    const float* key   = (const float*)d_in[1];
    const float* value = (const float*)d_in[2];
    const float* q_w   = (const float*)d_in[3];
    const float* k_w   = (const float*)d_in[4];
    const float* v_w   = (const float*)d_in[5];
    const float* out_w = (const float*)d_in[6];
    const float* ln_g  = (const float*)d_in[7];
    const float* ln_b  = (const float*)d_in[8];
    float* out = (float*)d_out;

    // workspace carve (xq slice 2 aliases opart: dead before attn writes it)
    char* p = (char*)d_ws;
    float* stats = (float*)p;  p += 256;
    short* wq_q = (short*)p;   p += (size_t)1024 * 1024 * 2;
    short* wq_k = (short*)p;   p += (size_t)512 * 1024 * 2;
    short* wq_v = (short*)p;   p += (size_t)512 * 1024 * 2;
    short* wq_o = (short*)p;   p += (size_t)1024 * 512 * 2;
    short* xq01 = (short*)p;   p += (size_t)2 * ROWS * E * 2;
    float* dqv  = (float*)p;   p += (size_t)3 * ROWS * 4;
    short* qb   = (short*)p;   p += (size_t)ROWS * E * 2;
    short* kb   = (short*)p;   p += (size_t)ROWS * KVE * 2;
    short* vb   = (short*)p;   p += (size_t)ROWS * KVE * 2;
    float* opart = (float*)p;  p += (size_t)2 * ROWS * KVE * 4;
    float* mlbuf = (float*)p;  p += (size_t)2 * ROWS * H * 2 * 4;
    short* xq2  = (short*)opart;  // alias: dead before attn runs
    if ((size_t)(p - (char*)d_ws) > ws_size) return;

    dim3 blk(256);
    hipMemsetAsync(stats, 0, 256, stream);
    wstats_kernel<<<dim3(64, 4), blk, 0, stream>>>(q_w, k_w, v_w, out_w,
        1024 * 1024, 512 * 1024, 512 * 1024, 1024 * 512, stats);
    wquant_kernel<<<dim3(64, 4), blk, 0, stream>>>(q_w, k_w, v_w, out_w,
        1024 * 1024, 512 * 1024, 512 * 1024, 1024 * 512, stats, wq_q, wq_k, wq_v, wq_o);

    aquant3_kernel<<<dim3(3 * ROWS / 4), blk, 0, stream>>>(query, key, value,
        xq01, xq2, dqv);
    gemm_qkv<<<dim3(1024), blk, 0, stream>>>(xq01, xq2, wq_q, wq_k, wq_v,
        dqv, stats, qb, kb, vb);

    attn_mfma<<<dim3(ROWS / 128, H, 2), blk, 0, stream>>>(qb, kb, vb, opart, mlbuf);

    ln_combine_kernel<<<dim3(ROWS / 4), blk, 0, stream>>>(opart, mlbuf,
        ln_g, ln_b, xq01, dqv);
    gemm_out<<<dim3(8, 64), blk, 0, stream>>>(xq01, wq_o, dqv, stats, out);
}

// Round 8
// 299.511 us; speedup vs baseline: 1.4339x; 1.1081x over previous
//
#include <hip/hip_runtime.h>
#include <cstdint>
#include <cstddef>

// Problem constants
constexpr int B_   = 4;
constexpr int SEQ  = 2048;
constexpr int E    = 1024;   // embed dim
constexpr int KVE  = 512;    // kv embed dim
constexpr int H    = 4;      // kv heads
constexpr int ROWS = B_ * SEQ;   // 8192 tokens

typedef short short8   __attribute__((ext_vector_type(8)));
typedef short short4v  __attribute__((ext_vector_type(4)));
typedef float floatx4  __attribute__((ext_vector_type(4)));
typedef float floatx16 __attribute__((ext_vector_type(16)));
typedef int   intx4    __attribute__((ext_vector_type(4)));

__device__ inline short f2bf(float f) {   // RNE float->bf16
    uint32_t u = __builtin_bit_cast(uint32_t, f);
    u = (u + 0x7fff + ((u >> 16) & 1)) >> 16;
    return (short)u;
}
__device__ inline float bf2f(short s) {
    return __builtin_bit_cast(float, (uint32_t)(uint16_t)s << 16);
}
__device__ inline void gl_lds16(const void* g, void* l) {
    __builtin_amdgcn_global_load_lds(
        (const __attribute__((address_space(1))) unsigned int*)g,
        (__attribute__((address_space(3))) unsigned int*)l, 16, 0, 0);
}

// ---------------------------------------------------------------------------
// Weight stats: per-matrix sum(w) and sum(|w|)
// ---------------------------------------------------------------------------
__global__ __launch_bounds__(256) void wstats_kernel(
    const float* __restrict__ w0, const float* __restrict__ w1,
    const float* __restrict__ w2, const float* __restrict__ w3,
    int n0, int n1, int n2, int n3, float* __restrict__ stats)
{
    int m = blockIdx.y;
    const float* w = (m == 0) ? w0 : (m == 1) ? w1 : (m == 2) ? w2 : w3;
    int n = (m == 0) ? n0 : (m == 1) ? n1 : (m == 2) ? n2 : n3;
    float s = 0.f, sa = 0.f;
    for (int i = blockIdx.x * 256 + threadIdx.x; i < n; i += gridDim.x * 256) {
        float x = w[i];
        s += x; sa += fabsf(x);
    }
#pragma unroll
    for (int o = 32; o; o >>= 1) { s += __shfl_xor(s, o); sa += __shfl_xor(sa, o); }
    __shared__ float ls[4], lsa[4];
    int lane = threadIdx.x & 63, wv = threadIdx.x >> 6;
    if (!lane) { ls[wv] = s; lsa[wv] = sa; }
    __syncthreads();
    if (!threadIdx.x) {
        atomicAdd(&stats[2 * m],     ls[0] + ls[1] + ls[2] + ls[3]);
        atomicAdd(&stats[2 * m + 1], lsa[0] + lsa[1] + lsa[2] + lsa[3]);
    }
}

// ---------------------------------------------------------------------------
// Weight ternary quant -> int8 {-1,0,+1} (packed 4-wide)
// ---------------------------------------------------------------------------
__global__ __launch_bounds__(256) void wquant_kernel(
    const float* __restrict__ w0, const float* __restrict__ w1,
    const float* __restrict__ w2, const float* __restrict__ w3,
    int n0, int n1, int n2, int n3, const float* __restrict__ stats,
    int8_t* __restrict__ o0, int8_t* __restrict__ o1,
    int8_t* __restrict__ o2, int8_t* __restrict__ o3)
{
    int m = blockIdx.y;
    const float* w = (m == 0) ? w0 : (m == 1) ? w1 : (m == 2) ? w2 : w3;
    int n = (m == 0) ? n0 : (m == 1) ? n1 : (m == 2) ? n2 : n3;
    int8_t* o = (m == 0) ? o0 : (m == 1) ? o1 : (m == 2) ? o2 : o3;
    float e = stats[2 * m] / (float)n;
    int n4 = n >> 2;
    for (int i = blockIdx.x * 256 + threadIdx.x; i < n4; i += gridDim.x * 256) {
        float4 x = ((const float4*)w)[i];
        int q0 = (x.x > e) - (x.x < e);
        int q1 = (x.y > e) - (x.y < e);
        int q2 = (x.z > e) - (x.z < e);
        int q3 = (x.w > e) - (x.w < e);
        uint32_t pk = (uint32_t)(q0 & 0xff) | ((uint32_t)(q1 & 0xff) << 8) |
                      ((uint32_t)(q2 & 0xff) << 16) | ((uint32_t)(q3 & 0xff) << 24);
        *(uint32_t*)(o + ((size_t)i << 2)) = pk;
    }
}

// ---------------------------------------------------------------------------
// Activation quant, wave-per-row (no barriers): RMSNorm -> packed int8
// Block = 4 waves = 4 rows. Grid 3*ROWS/4. Lane owns cols lane*4 + j*256.
// ---------------------------------------------------------------------------
__global__ __launch_bounds__(256) void aquant3_kernel(
    const float* __restrict__ q, const float* __restrict__ k,
    const float* __restrict__ vv, int8_t* __restrict__ xq01,
    int8_t* __restrict__ xq2, float* __restrict__ dqv)
{
    int lane = threadIdx.x & 63, wv = threadIdx.x >> 6;
    int rowi = blockIdx.x * 4 + wv;
    int z = rowi >> 13, r = rowi & (ROWS - 1);
    const float* x = (z == 0) ? q : (z == 1) ? k : vv;
    int8_t* xq = (z == 2) ? xq2 : xq01 + (size_t)z * ROWS * E;
    size_t base = (size_t)r * E;
    float4 v[4];
    float ss = 0.f, am = 0.f;
#pragma unroll
    for (int j = 0; j < 4; j++) {
        v[j] = *(const float4*)(x + base + lane * 4 + j * 256);
        ss += v[j].x * v[j].x + v[j].y * v[j].y + v[j].z * v[j].z + v[j].w * v[j].w;
        am = fmaxf(am, fmaxf(fmaxf(fabsf(v[j].x), fabsf(v[j].y)),
                             fmaxf(fabsf(v[j].z), fabsf(v[j].w))));
    }
#pragma unroll
    for (int o = 32; o; o >>= 1) { ss += __shfl_xor(ss, o); am = fmaxf(am, __shfl_xor(am, o)); }
    float rms = rsqrtf(ss * (1.0f / E) + 1e-6f);
    float cl  = fmaxf(am * rms, 1e-5f);
    float kf  = rms * (127.0f / cl);
#pragma unroll
    for (int j = 0; j < 4; j++) {
        int q0 = max(-128, min(127, (int)rintf(v[j].x * kf)));
        int q1 = max(-128, min(127, (int)rintf(v[j].y * kf)));
        int q2 = max(-128, min(127, (int)rintf(v[j].z * kf)));
        int q3 = max(-128, min(127, (int)rintf(v[j].w * kf)));
        uint32_t pk = (uint32_t)(q0 & 0xff) | ((uint32_t)(q1 & 0xff) << 8) |
                      ((uint32_t)(q2 & 0xff) << 16) | ((uint32_t)(q3 & 0xff) << 24);
        *(uint32_t*)(xq + base + lane * 4 + j * 256) = pk;
    }
    if (!lane) dqv[(size_t)z * ROWS + r] = cl * (1.0f / 127.0f);
}

// ---------------------------------------------------------------------------
// int8 MFMA GEMM body (exact i32 accumulate). 128x128 tile, BK=64,
// global_load_lds w16, chunk-XOR swizzle (identical 64B-row geometry to the
// verified bf16 version; mfma_i32_16x16x64_i8, 16 bytes/lane per fragment).
// ---------------------------------------------------------------------------
template <bool F32OUT>
__device__ inline void gemm_body(
    const int8_t* __restrict__ A, const int8_t* __restrict__ W,
    const float* __restrict__ dqv, float sw, void* __restrict__ Cout,
    int O, int K, int8_t* As, int8_t* Ws, size_t row0, size_t c0)
{
    int tid = threadIdx.x;
    int w = tid >> 6, lane = tid & 63;
    int quad = lane >> 4, l15 = lane & 15;
    int mbase = (w & 1) * 64, nbase = (w >> 1) * 64;

    intx4 acc[4][4];
#pragma unroll
    for (int i = 0; i < 4; i++)
#pragma unroll
        for (int j = 0; j < 4; j++) acc[i][j] = (intx4){0, 0, 0, 0};

    // chunk c (16 B): row = c>>2, LDS pos = c&3 holds global k-chunk (pos^(row&3))
    int cA0 = tid, cA1 = tid + 256;
    int rA0 = cA0 >> 2, gA0 = (cA0 & 3) ^ (rA0 & 3);
    int rA1 = cA1 >> 2, gA1 = (cA1 & 3) ^ (rA1 & 3);
    const int8_t* Ag0 = A + (row0 + rA0) * K + gA0 * 16;
    const int8_t* Ag1 = A + (row0 + rA1) * K + gA1 * 16;
    const int8_t* Wg0 = W + (c0 + rA0) * K + gA0 * 16;
    const int8_t* Wg1 = W + (c0 + rA1) * K + gA1 * 16;
    int8_t* lA0 = As + cA0 * 16;  int8_t* lA1 = As + cA1 * 16;
    int8_t* lW0 = Ws + cA0 * 16;  int8_t* lW1 = Ws + cA1 * 16;

    for (int kt = 0; kt < K; kt += 64) {
        __syncthreads();
        gl_lds16(Ag0 + kt, lA0);
        gl_lds16(Ag1 + kt, lA1);
        gl_lds16(Wg0 + kt, lW0);
        gl_lds16(Wg1 + kt, lW1);
        __syncthreads();
        intx4 af[4], bfr[4];
#pragma unroll
        for (int mt = 0; mt < 4; mt++) {
            int row = mbase + mt * 16 + l15;
            int pos = quad ^ (row & 3);
            af[mt] = *(const intx4*)(As + row * 64 + pos * 16);
        }
#pragma unroll
        for (int nt = 0; nt < 4; nt++) {
            int row = nbase + nt * 16 + l15;
            int pos = quad ^ (row & 3);
            bfr[nt] = *(const intx4*)(Ws + row * 64 + pos * 16);
        }
#pragma unroll
        for (int mt = 0; mt < 4; mt++)
#pragma unroll
            for (int nt = 0; nt < 4; nt++)
                acc[mt][nt] = __builtin_amdgcn_mfma_i32_16x16x64_i8(
                    af[mt], bfr[nt], acc[mt][nt], 0, 0, 0);
    }

#pragma unroll
    for (int mt = 0; mt < 4; mt++) {
#pragma unroll
        for (int r = 0; r < 4; r++) {
            size_t grow = row0 + mbase + mt * 16 + quad * 4 + r;
            float scv = sw * dqv[grow];
#pragma unroll
            for (int nt = 0; nt < 4; nt++) {
                size_t gcol = c0 + nbase + nt * 16 + l15;
                float v = (float)acc[mt][nt][r] * scv;
                if constexpr (F32OUT) ((float*)Cout)[grow * O + gcol] = v;
                else                  ((short*)Cout)[grow * O + gcol] = f2bf(v);
            }
        }
    }
}

// Batched QKV GEMM: flat 1024-block grid (512 q / 256 k / 256 v tiles).
__global__ __launch_bounds__(256) void gemm_qkv(
    const int8_t* __restrict__ xq01, const int8_t* __restrict__ xq2,
    const int8_t* __restrict__ wq_q, const int8_t* __restrict__ wq_k,
    const int8_t* __restrict__ wq_v, const float* __restrict__ dqv,
    const float* __restrict__ stats,
    short* __restrict__ qb, short* __restrict__ kb, short* __restrict__ vb)
{
    __shared__ int8_t As[128 * 64];
    __shared__ int8_t Ws[128 * 64];
    int id = blockIdx.x;
    int z, bx, by;
    if (id < 512)      { z = 0; bx = id & 7; by = id >> 3; }
    else if (id < 768) { z = 1; int t = id - 512; bx = t & 3; by = t >> 2; }
    else               { z = 2; int t = id - 768; bx = t & 3; by = t >> 2; }
    int O = z ? KVE : E;
    const int8_t* A = (z == 0) ? xq01 : (z == 1) ? xq01 + (size_t)ROWS * E : xq2;
    const int8_t* W = (z == 0) ? wq_q : (z == 1) ? wq_k : wq_v;
    short* outp = (z == 0) ? qb : (z == 1) ? kb : vb;
    float sw = stats[2 * z + 1] / (float)(O * E);
    gemm_body<false>(A, W, dqv + (size_t)z * ROWS, sw, outp, O, E, As, Ws,
                     (size_t)by * 128, (size_t)bx * 128);
}

// Output GEMM (fp32 out, K=512)
__global__ __launch_bounds__(256) void gemm_out(
    const int8_t* __restrict__ A, const int8_t* __restrict__ W,
    const float* __restrict__ dqv, const float* __restrict__ stats,
    float* __restrict__ Cout)
{
    __shared__ int8_t As[128 * 64];
    __shared__ int8_t Ws[128 * 64];
    float sw = stats[7] / (float)(E * KVE);
    gemm_body<true>(A, W, dqv, sw, Cout, E, KVE, As, Ws,
                    (size_t)blockIdx.y * 128, (size_t)blockIdx.x * 128);
}

// ---------------------------------------------------------------------------
// MFMA flash attention v5: 32x32x16 MFMA, S^T orientation, per-lane scalar
// softmax (1 shuffle), Q frags from global. Block: 128 q-rows x head x
// KV-half. Wave owns 32 q-cols. Grid (64, H, 2). [HW-verified R6/R7]
// ---------------------------------------------------------------------------
__global__ __launch_bounds__(256, 2) void attn_mfma(
    const short* __restrict__ qb, const short* __restrict__ kb,
    const short* __restrict__ vb, float* __restrict__ opart,
    float* __restrict__ mlbuf)
{
    __shared__ short Ks[64][132];
    __shared__ short Vt[128][68];
    __shared__ short Ps[128][68];
    int tid = threadIdx.x;
    int w = tid >> 6, lane = tid & 63;
    int l31 = lane & 31, hi = lane >> 5;
    int blk = blockIdx.x, h = blockIdx.y, half = blockIdx.z;
    int b = blk >> 4;                       // 16 q-tiles of 128 per batch
    size_t qrow0 = (size_t)blk * 128;
    size_t sbase = (size_t)b * SEQ + (size_t)half * (SEQ / 2);

    int sK = tid >> 2, cK = tid & 3;          // K staging: row, 32-col chunk
    int sV = (tid & 15) * 4, dV = tid >> 4;   // V staging: 4 rows, 8-col chunk

    // ---- prefetch KV tile 0 into registers
    short8 kreg[4], vreg[4];
    {
        const short* ksrc = kb + (sbase + sK) * KVE + h * 128 + cK * 32;
#pragma unroll
        for (int j = 0; j < 4; j++) kreg[j] = *(const short8*)(ksrc + j * 8);
        const short* vsrc = vb + (sbase + sV) * KVE + h * 128 + dV * 8;
#pragma unroll
        for (int j = 0; j < 4; j++) vreg[j] = *(const short8*)(vsrc + j * KVE);
    }

    // ---- Q^T B-frags straight from global: head-pair sum, fold 1/128
    short8 qfrag[8];
    {
        const short* src = qb + (qrow0 + w * 32 + l31) * E + h * 256 + hi * 8;
#pragma unroll
        for (int j = 0; j < 8; j++) {
            short8 a  = *(const short8*)(src + j * 16);
            short8 b2 = *(const short8*)(src + j * 16 + 128);
            short8 o;
#pragma unroll
            for (int e = 0; e < 8; e++)
                o[e] = f2bf((bf2f(a[e]) + bf2f(b2[e])) * (1.0f / 128.0f));
            qfrag[j] = o;
        }
    }

    floatx16 oacc[4];
#pragma unroll
    for (int dt = 0; dt < 4; dt++)
#pragma unroll
        for (int r = 0; r < 16; r++) oacc[dt][r] = 0.f;
    float m_s = -1e30f, l_s = 0.f;

    for (int st = 0; st < SEQ / 128; st++) {
        __syncthreads();   // prior readers of Ks/Vt done
        // commit prefetched K tile
#pragma unroll
        for (int j = 0; j < 4; j++)
            *(short8*)&Ks[sK][cK * 32 + j * 8] = kreg[j];
        // commit prefetched V tile (transposed)
#pragma unroll
        for (int i = 0; i < 8; i++) {
            short4v vv = { vreg[0][i], vreg[1][i], vreg[2][i], vreg[3][i] };
            *(short4v*)&Vt[dV * 8 + i][sV] = vv;
        }
        // issue next tile's global loads
        if (st + 1 < SEQ / 128) {
            size_t srow0 = sbase + (size_t)(st + 1) * 64;
            const short* ksrc = kb + (srow0 + sK) * KVE + h * 128 + cK * 32;
#pragma unroll
            for (int j = 0; j < 4; j++) kreg[j] = *(const short8*)(ksrc + j * 8);
            const short* vsrc = vb + (srow0 + sV) * KVE + h * 128 + dV * 8;
#pragma unroll
            for (int j = 0; j < 4; j++) vreg[j] = *(const short8*)(vsrc + j * KVE);
        }
        __syncthreads();
        // S^T = K * Q^T: two 32x32 tiles (keys 0-31, 32-63) x 32 q-cols
        floatx16 sc0, sc1;
#pragma unroll
        for (int r = 0; r < 16; r++) { sc0[r] = 0.f; sc1[r] = 0.f; }
#pragma unroll
        for (int j = 0; j < 8; j++) {
            short8 kf0 = *(const short8*)&Ks[l31][j * 16 + hi * 8];
            short8 kf1 = *(const short8*)&Ks[32 + l31][j * 16 + hi * 8];
            sc0 = __builtin_amdgcn_mfma_f32_32x32x16_bf16(kf0, qfrag[j], sc0, 0, 0, 0);
            sc1 = __builtin_amdgcn_mfma_f32_32x32x16_bf16(kf1, qfrag[j], sc1, 0, 0, 0);
        }
        // online softmax: lane + lane^32 together hold all 64 keys for this q
        float mx = sc0[0];
#pragma unroll
        for (int r = 0; r < 16; r++) { mx = fmaxf(mx, sc0[r]); mx = fmaxf(mx, sc1[r]); }
        mx = fmaxf(mx, __shfl_xor(mx, 32));
        float nm = fmaxf(m_s, mx);
        float alpha = __expf(m_s - nm);
        m_s = nm;
        float rs = 0.f;
#pragma unroll
        for (int r = 0; r < 16; r++) {
            float p0 = __expf(sc0[r] - nm); sc0[r] = p0; rs += p0;
            float p1 = __expf(sc1[r] - nm); sc1[r] = p1; rs += p1;
        }
        rs += __shfl_xor(rs, 32);
        l_s = l_s * alpha + rs;
        // P -> LDS: regs c*4..c*4+3 are consecutive keys 8c+4hi(+t*32)
        int qrow = w * 32 + l31;
#pragma unroll
        for (int c = 0; c < 4; c++) {
            short4v p0 = { f2bf(sc0[c * 4]), f2bf(sc0[c * 4 + 1]),
                           f2bf(sc0[c * 4 + 2]), f2bf(sc0[c * 4 + 3]) };
            *(short4v*)&Ps[qrow][c * 8 + hi * 4] = p0;
            short4v p1 = { f2bf(sc1[c * 4]), f2bf(sc1[c * 4 + 1]),
                           f2bf(sc1[c * 4 + 2]), f2bf(sc1[c * 4 + 3]) };
            *(short4v*)&Ps[qrow][32 + c * 8 + hi * 4] = p1;
        }
        // rescale O^T
#pragma unroll
        for (int dt = 0; dt < 4; dt++)
#pragma unroll
            for (int r = 0; r < 16; r++) oacc[dt][r] *= alpha;
        // PV: O^T = V^T * P^T (A = Vt frag, B = P^T frag; same-wave LDS RAW)
        short8 pb[4];
#pragma unroll
        for (int j = 0; j < 4; j++)
            pb[j] = *(const short8*)&Ps[qrow][j * 16 + hi * 8];
#pragma unroll
        for (int dt = 0; dt < 4; dt++)
#pragma unroll
            for (int j = 0; j < 4; j++) {
                short8 vf = *(const short8*)&Vt[dt * 32 + l31][j * 16 + hi * 8];
                oacc[dt] = __builtin_amdgcn_mfma_f32_32x32x16_bf16(vf, pb[j], oacc[dt], 0, 0, 0);
            }
    }
    // epilogue: normalized partial O + (m,l)
    {
        float inv = 1.0f / l_s;
        size_t grow = qrow0 + w * 32 + l31;
        float* dst = opart + ((size_t)half * ROWS + grow) * KVE + h * 128;
#pragma unroll
        for (int dt = 0; dt < 4; dt++)
#pragma unroll
            for (int c = 0; c < 4; c++) {
                float4 o4 = { oacc[dt][c * 4] * inv, oacc[dt][c * 4 + 1] * inv,
                              oacc[dt][c * 4 + 2] * inv, oacc[dt][c * 4 + 3] * inv };
                *(float4*)(dst + dt * 32 + c * 8 + hi * 4) = o4;
            }
        if (hi == 0) {
            float* ml = mlbuf + (((size_t)half * ROWS + grow) * H + h) * 2;
            ml[0] = m_s;
            ml[1] = l_s;
        }
    }
}

// ---------------------------------------------------------------------------
// Partial combine + LayerNorm + RMSNorm + int8 quant (packed), wave-per-row.
// Block = 4 waves = 4 rows, grid ROWS/4. Lane owns cols lane*4 + j*256.
// ---------------------------------------------------------------------------
__global__ __launch_bounds__(256) void ln_combine_kernel(
    const float* __restrict__ opart, const float* __restrict__ mlbuf,
    const float* __restrict__ gamma, const float* __restrict__ beta,
    int8_t* __restrict__ xq, float* __restrict__ dqv)
{
    int lane = threadIdx.x & 63, wv = threadIdx.x >> 6;
    int row = blockIdx.x * 4 + wv;
    float4 y[2];
    float s = 0.f, ss = 0.f;
#pragma unroll
    for (int j = 0; j < 2; j++) {
        int col = lane * 4 + j * 256;
        int h = j * 2 + (lane >> 5);
        const float* ml0 = mlbuf + ((size_t)row * H + h) * 2;
        const float* ml1 = mlbuf + (((size_t)ROWS + row) * H + h) * 2;
        float m1 = ml0[0], l1v = ml0[1], m2 = ml1[0], l2v = ml1[1];
        float M = fmaxf(m1, m2);
        float w1 = l1v * __expf(m1 - M), w2 = l2v * __expf(m2 - M);
        float winv = 1.0f / (w1 + w2);
        w1 *= winv; w2 *= winv;
        float4 o1 = *(const float4*)(opart + (size_t)row * KVE + col);
        float4 o2 = *(const float4*)(opart + ((size_t)ROWS + row) * KVE + col);
        float4 vv = { o1.x * w1 + o2.x * w2, o1.y * w1 + o2.y * w2,
                      o1.z * w1 + o2.z * w2, o1.w * w1 + o2.w * w2 };
        y[j] = vv;
        s += vv.x + vv.y + vv.z + vv.w;
        ss += vv.x * vv.x + vv.y * vv.y + vv.z * vv.z + vv.w * vv.w;
    }
#pragma unroll
    for (int o = 32; o; o >>= 1) { s += __shfl_xor(s, o); ss += __shfl_xor(ss, o); }
    float mu = s * (1.0f / KVE);
    float var = fmaxf(ss * (1.0f / KVE) - mu * mu, 0.0f);
    float inv = rsqrtf(var + 1e-5f);
    float sy = 0.f, am = 0.f;
#pragma unroll
    for (int j = 0; j < 2; j++) {
        int col = lane * 4 + j * 256;
        float4 g = *(const float4*)(gamma + col);
        float4 be = *(const float4*)(beta + col);
        y[j].x = (y[j].x - mu) * inv * g.x + be.x;
        y[j].y = (y[j].y - mu) * inv * g.y + be.y;
        y[j].z = (y[j].z - mu) * inv * g.z + be.z;
        y[j].w = (y[j].w - mu) * inv * g.w + be.w;
        sy += y[j].x * y[j].x + y[j].y * y[j].y + y[j].z * y[j].z + y[j].w * y[j].w;
        am = fmaxf(am, fmaxf(fmaxf(fabsf(y[j].x), fabsf(y[j].y)),
                             fmaxf(fabsf(y[j].z), fabsf(y[j].w))));
    }
#pragma unroll
    for (int o = 32; o; o >>= 1) { sy += __shfl_xor(sy, o); am = fmaxf(am, __shfl_xor(am, o)); }
    float rms = rsqrtf(sy * (1.0f / KVE) + 1e-6f);
    float cl = fmaxf(am * rms, 1e-5f);
    float kf = rms * (127.0f / cl);
#pragma unroll
    for (int j = 0; j < 2; j++) {
        int col = lane * 4 + j * 256;
        int q0 = max(-128, min(127, (int)rintf(y[j].x * kf)));
        int q1 = max(-128, min(127, (int)rintf(y[j].y * kf)));
        int q2 = max(-128, min(127, (int)rintf(y[j].z * kf)));
        int q3 = max(-128, min(127, (int)rintf(y[j].w * kf)));
        uint32_t pk = (uint32_t)(q0 & 0xff) | ((uint32_t)(q1 & 0xff) << 8) |
                      ((uint32_t)(q2 & 0xff) << 16) | ((uint32_t)(q3 & 0xff) << 24);
        *(uint32_t*)(xq + (size_t)row * KVE + col) = pk;
    }
    if (!lane) dqv[row] = cl * (1.0f / 127.0f);
}

// ---------------------------------------------------------------------------
extern "C" void kernel_launch(void* const* d_in, const int* in_sizes, int n_in,
                              void* d_out, int out_size, void* d_ws, size_t ws_size,
                              hipStream_t stream)
{
    const float* query = (const float*)d_in[0];
    const float* key   = (const float*)d_in[1];
    const float* value = (const float*)d_in[2];
    const float* q_w   = (const float*)d_in[3];
    const float* k_w   = (const float*)d_in[4];
    const float* v_w   = (const float*)d_in[5];
    const float* out_w = (const float*)d_in[6];
    const float* ln_g  = (const float*)d_in[7];
    const float* ln_b  = (const float*)d_in[8];
    float* out = (float*)d_out;

    // workspace carve (xq slice 2 aliases opart: dead before attn writes it)
    char* p = (char*)d_ws;
    float* stats = (float*)p;  p += 256;
    int8_t* wq_q = (int8_t*)p; p += (size_t)1024 * 1024;
    int8_t* wq_k = (int8_t*)p; p += (size_t)512 * 1024;
    int8_t* wq_v = (int8_t*)p; p += (size_t)512 * 1024;
    int8_t* wq_o = (int8_t*)p; p += (size_t)1024 * 512;
    int8_t* xq01 = (int8_t*)p; p += (size_t)2 * ROWS * E;
    float* dqv  = (float*)p;   p += (size_t)3 * ROWS * 4;
    short* qb   = (short*)p;   p += (size_t)ROWS * E * 2;
    short* kb   = (short*)p;   p += (size_t)ROWS * KVE * 2;
    short* vb   = (short*)p;   p += (size_t)ROWS * KVE * 2;
    float* opart = (float*)p;  p += (size_t)2 * ROWS * KVE * 4;
    float* mlbuf = (float*)p;  p += (size_t)2 * ROWS * H * 2 * 4;
    int8_t* xq2 = (int8_t*)opart;  // alias: 8 MB, dead before attn runs
    if ((size_t)(p - (char*)d_ws) > ws_size) return;

    dim3 blk(256);
    hipMemsetAsync(stats, 0, 256, stream);
    wstats_kernel<<<dim3(64, 4), blk, 0, stream>>>(q_w, k_w, v_w, out_w,
        1024 * 1024, 512 * 1024, 512 * 1024, 1024 * 512, stats);
    wquant_kernel<<<dim3(64, 4), blk, 0, stream>>>(q_w, k_w, v_w, out_w,
        1024 * 1024, 512 * 1024, 512 * 1024, 1024 * 512, stats, wq_q, wq_k, wq_v, wq_o);

    aquant3_kernel<<<dim3(3 * ROWS / 4), blk, 0, stream>>>(query, key, value,
        xq01, xq2, dqv);
    gemm_qkv<<<dim3(1024), blk, 0, stream>>>(xq01, xq2, wq_q, wq_k, wq_v,
        dqv, stats, qb, kb, vb);

    attn_mfma<<<dim3(ROWS / 128, H, 2), blk, 0, stream>>>(qb, kb, vb, opart, mlbuf);

    ln_combine_kernel<<<dim3(ROWS / 4), blk, 0, stream>>>(opart, mlbuf,
        ln_g, ln_b, xq01, dqv);
    gemm_out<<<dim3(8, 64), blk, 0, stream>>>(xq01, wq_o, dqv, stats, out);
}

// Round 9
// 266.579 us; speedup vs baseline: 1.6110x; 1.1235x over previous
//
#include <hip/hip_runtime.h>
#include <cstdint>
#include <cstddef>

// Problem constants
constexpr int B_   = 4;
constexpr int SEQ  = 2048;
constexpr int E    = 1024;   // embed dim
constexpr int KVE  = 512;    // kv embed dim
constexpr int H    = 4;      // kv heads
constexpr int ROWS = B_ * SEQ;   // 8192 tokens

typedef short short8   __attribute__((ext_vector_type(8)));
typedef short short4v  __attribute__((ext_vector_type(4)));
typedef float floatx4  __attribute__((ext_vector_type(4)));
typedef float floatx16 __attribute__((ext_vector_type(16)));
typedef int   intx4    __attribute__((ext_vector_type(4)));

__device__ inline short f2bf(float f) {   // RNE float->bf16
    uint32_t u = __builtin_bit_cast(uint32_t, f);
    u = (u + 0x7fff + ((u >> 16) & 1)) >> 16;
    return (short)u;
}
__device__ inline float bf2f(short s) {
    return __builtin_bit_cast(float, (uint32_t)(uint16_t)s << 16);
}
__device__ inline void gl_lds16(const void* g, void* l) {
    __builtin_amdgcn_global_load_lds(
        (const __attribute__((address_space(1))) unsigned int*)g,
        (__attribute__((address_space(3))) unsigned int*)l, 16, 0, 0);
}

// ---------------------------------------------------------------------------
// Merged pre-pass: blocks [0,256) do weight stats (float4, atomicAdd);
// blocks [256, 6400) do activation RMSNorm+int8 quant (wave-per-row).
// The two halves are INDEPENDENT work (no intra-kernel ordering) — this is
// grid concatenation, not the R6 serial-fusion mistake.
// ---------------------------------------------------------------------------
__global__ __launch_bounds__(256) void pre_kernel(
    const float* __restrict__ qx, const float* __restrict__ kx,
    const float* __restrict__ vx,
    const float* __restrict__ w0, const float* __restrict__ w1,
    const float* __restrict__ w2, const float* __restrict__ w3,
    int8_t* __restrict__ xq01, int8_t* __restrict__ xq2,
    float* __restrict__ dqv, float* __restrict__ stats)
{
    int tid = threadIdx.x, bid = blockIdx.x;
    int lane = tid & 63, wv = tid >> 6;
    if (bid < 256) {
        // ---- weight stats, float4 grid-stride
        int m = bid >> 6;
        const float* w = (m == 0) ? w0 : (m == 1) ? w1 : (m == 2) ? w2 : w3;
        int n4 = ((m == 0) ? 1024 * 1024 : 512 * 1024) >> 2;
        float s = 0.f, sa = 0.f;
        for (int i = (bid & 63) * 256 + tid; i < n4; i += 64 * 256) {
            float4 x = ((const float4*)w)[i];
            s += x.x + x.y + x.z + x.w;
            sa += fabsf(x.x) + fabsf(x.y) + fabsf(x.z) + fabsf(x.w);
        }
#pragma unroll
        for (int o = 32; o; o >>= 1) { s += __shfl_xor(s, o); sa += __shfl_xor(sa, o); }
        __shared__ float ls[4], lsa[4];
        if (!lane) { ls[wv] = s; lsa[wv] = sa; }
        __syncthreads();
        if (!tid) {
            atomicAdd(&stats[2 * m],     ls[0] + ls[1] + ls[2] + ls[3]);
            atomicAdd(&stats[2 * m + 1], lsa[0] + lsa[1] + lsa[2] + lsa[3]);
        }
        return;
    }
    // ---- activation quant, wave-per-row (no barriers)
    int rowi = (bid - 256) * 4 + wv;
    int z = rowi >> 13, r = rowi & (ROWS - 1);
    const float* x = (z == 0) ? qx : (z == 1) ? kx : vx;
    int8_t* xq = (z == 2) ? xq2 : xq01 + (size_t)z * ROWS * E;
    size_t base = (size_t)r * E;
    float4 v[4];
    float ss = 0.f, am = 0.f;
#pragma unroll
    for (int j = 0; j < 4; j++) {
        v[j] = *(const float4*)(x + base + lane * 4 + j * 256);
        ss += v[j].x * v[j].x + v[j].y * v[j].y + v[j].z * v[j].z + v[j].w * v[j].w;
        am = fmaxf(am, fmaxf(fmaxf(fabsf(v[j].x), fabsf(v[j].y)),
                             fmaxf(fabsf(v[j].z), fabsf(v[j].w))));
    }
#pragma unroll
    for (int o = 32; o; o >>= 1) { ss += __shfl_xor(ss, o); am = fmaxf(am, __shfl_xor(am, o)); }
    float rms = rsqrtf(ss * (1.0f / E) + 1e-6f);
    float cl  = fmaxf(am * rms, 1e-5f);
    float kf  = rms * (127.0f / cl);
#pragma unroll
    for (int j = 0; j < 4; j++) {
        int q0 = max(-128, min(127, (int)rintf(v[j].x * kf)));
        int q1 = max(-128, min(127, (int)rintf(v[j].y * kf)));
        int q2 = max(-128, min(127, (int)rintf(v[j].z * kf)));
        int q3 = max(-128, min(127, (int)rintf(v[j].w * kf)));
        uint32_t pk = (uint32_t)(q0 & 0xff) | ((uint32_t)(q1 & 0xff) << 8) |
                      ((uint32_t)(q2 & 0xff) << 16) | ((uint32_t)(q3 & 0xff) << 24);
        *(uint32_t*)(xq + base + lane * 4 + j * 256) = pk;
    }
    if (!lane) dqv[(size_t)z * ROWS + r] = cl * (1.0f / 127.0f);
}

// ---------------------------------------------------------------------------
// Weight ternary quant -> int8 {-1,0,+1} (packed 4-wide)
// ---------------------------------------------------------------------------
__global__ __launch_bounds__(256) void wquant_kernel(
    const float* __restrict__ w0, const float* __restrict__ w1,
    const float* __restrict__ w2, const float* __restrict__ w3,
    int n0, int n1, int n2, int n3, const float* __restrict__ stats,
    int8_t* __restrict__ o0, int8_t* __restrict__ o1,
    int8_t* __restrict__ o2, int8_t* __restrict__ o3)
{
    int m = blockIdx.y;
    const float* w = (m == 0) ? w0 : (m == 1) ? w1 : (m == 2) ? w2 : w3;
    int n = (m == 0) ? n0 : (m == 1) ? n1 : (m == 2) ? n2 : n3;
    int8_t* o = (m == 0) ? o0 : (m == 1) ? o1 : (m == 2) ? o2 : o3;
    float e = stats[2 * m] / (float)n;
    int n4 = n >> 2;
    for (int i = blockIdx.x * 256 + threadIdx.x; i < n4; i += gridDim.x * 256) {
        float4 x = ((const float4*)w)[i];
        int q0 = (x.x > e) - (x.x < e);
        int q1 = (x.y > e) - (x.y < e);
        int q2 = (x.z > e) - (x.z < e);
        int q3 = (x.w > e) - (x.w < e);
        uint32_t pk = (uint32_t)(q0 & 0xff) | ((uint32_t)(q1 & 0xff) << 8) |
                      ((uint32_t)(q2 & 0xff) << 16) | ((uint32_t)(q3 & 0xff) << 24);
        *(uint32_t*)(o + ((size_t)i << 2)) = pk;
    }
}

// ---------------------------------------------------------------------------
// int8 MFMA GEMM body (exact i32 accumulate). 128x128 tile, BK=128 (8 chunk
// positions, XOR (row&7) swizzle), global_load_lds w16, 2 K-halves per stage.
// ---------------------------------------------------------------------------
template <bool F32OUT>
__device__ inline void gemm_body(
    const int8_t* __restrict__ A, const int8_t* __restrict__ W,
    const float* __restrict__ dqv, float sw, void* __restrict__ Cout,
    int O, int K, int8_t* As, int8_t* Ws, size_t row0, size_t c0)
{
    int tid = threadIdx.x;
    int w = tid >> 6, lane = tid & 63;
    int quad = lane >> 4, l15 = lane & 15;
    int mbase = (w & 1) * 64, nbase = (w >> 1) * 64;

    intx4 acc[4][4];
#pragma unroll
    for (int i = 0; i < 4; i++)
#pragma unroll
        for (int j = 0; j < 4; j++) acc[i][j] = (intx4){0, 0, 0, 0};

    // staging: 4 chunks (16 B) per thread per matrix; chunk c: row=c>>3,
    // LDS pos=c&7 holds global k-chunk (pos ^ (row&7))
    const int8_t* Ag[4]; const int8_t* Wg[4]; int8_t* lA[4]; int8_t* lW[4];
#pragma unroll
    for (int t = 0; t < 4; t++) {
        int c = tid + t * 256;
        int row = c >> 3, g = (c & 7) ^ (row & 7);
        Ag[t] = A + (row0 + row) * K + g * 16;
        Wg[t] = W + (c0 + row) * K + g * 16;
        lA[t] = As + c * 16;
        lW[t] = Ws + c * 16;
    }

    for (int kt = 0; kt < K; kt += 128) {
        __syncthreads();
#pragma unroll
        for (int t = 0; t < 4; t++) {
            gl_lds16(Ag[t] + kt, lA[t]);
            gl_lds16(Wg[t] + kt, lW[t]);
        }
        __syncthreads();
#pragma unroll
        for (int kh = 0; kh < 2; kh++) {
            intx4 af[4], bfr[4];
#pragma unroll
            for (int mt = 0; mt < 4; mt++) {
                int row = mbase + mt * 16 + l15;
                int pos = (quad + 4 * kh) ^ (row & 7);
                af[mt] = *(const intx4*)(As + row * 128 + pos * 16);
            }
#pragma unroll
            for (int nt = 0; nt < 4; nt++) {
                int row = nbase + nt * 16 + l15;
                int pos = (quad + 4 * kh) ^ (row & 7);
                bfr[nt] = *(const intx4*)(Ws + row * 128 + pos * 16);
            }
#pragma unroll
            for (int mt = 0; mt < 4; mt++)
#pragma unroll
                for (int nt = 0; nt < 4; nt++)
                    acc[mt][nt] = __builtin_amdgcn_mfma_i32_16x16x64_i8(
                        af[mt], bfr[nt], acc[mt][nt], 0, 0, 0);
        }
    }

#pragma unroll
    for (int mt = 0; mt < 4; mt++) {
#pragma unroll
        for (int r = 0; r < 4; r++) {
            size_t grow = row0 + mbase + mt * 16 + quad * 4 + r;
            float scv = sw * dqv[grow];
#pragma unroll
            for (int nt = 0; nt < 4; nt++) {
                size_t gcol = c0 + nbase + nt * 16 + l15;
                float v = (float)acc[mt][nt][r] * scv;
                if constexpr (F32OUT) ((float*)Cout)[grow * O + gcol] = v;
                else                  ((short*)Cout)[grow * O + gcol] = f2bf(v);
            }
        }
    }
}

// Batched QKV GEMM: flat 1024-block grid (512 q / 256 k / 256 v tiles).
__global__ __launch_bounds__(256) void gemm_qkv(
    const int8_t* __restrict__ xq01, const int8_t* __restrict__ xq2,
    const int8_t* __restrict__ wq_q, const int8_t* __restrict__ wq_k,
    const int8_t* __restrict__ wq_v, const float* __restrict__ dqv,
    const float* __restrict__ stats,
    short* __restrict__ qb, short* __restrict__ kb, short* __restrict__ vb)
{
    __shared__ int8_t As[128 * 128];
    __shared__ int8_t Ws[128 * 128];
    int id = blockIdx.x;
    int z, bx, by;
    if (id < 512)      { z = 0; bx = id & 7; by = id >> 3; }
    else if (id < 768) { z = 1; int t = id - 512; bx = t & 3; by = t >> 2; }
    else               { z = 2; int t = id - 768; bx = t & 3; by = t >> 2; }
    int O = z ? KVE : E;
    const int8_t* A = (z == 0) ? xq01 : (z == 1) ? xq01 + (size_t)ROWS * E : xq2;
    const int8_t* W = (z == 0) ? wq_q : (z == 1) ? wq_k : wq_v;
    short* outp = (z == 0) ? qb : (z == 1) ? kb : vb;
    float sw = stats[2 * z + 1] / (float)(O * E);
    gemm_body<false>(A, W, dqv + (size_t)z * ROWS, sw, outp, O, E, As, Ws,
                     (size_t)by * 128, (size_t)bx * 128);
}

// Output GEMM (fp32 out, K=512)
__global__ __launch_bounds__(256) void gemm_out(
    const int8_t* __restrict__ A, const int8_t* __restrict__ W,
    const float* __restrict__ dqv, const float* __restrict__ stats,
    float* __restrict__ Cout)
{
    __shared__ int8_t As[128 * 128];
    __shared__ int8_t Ws[128 * 128];
    float sw = stats[7] / (float)(E * KVE);
    gemm_body<true>(A, W, dqv, sw, Cout, E, KVE, As, Ws,
                    (size_t)blockIdx.y * 128, (size_t)blockIdx.x * 128);
}

// ---------------------------------------------------------------------------
// MFMA flash attention v5b: 32x32x16 MFMA, S^T orientation, per-lane scalar
// softmax (1 shuffle), Q frags from global, bf16 partial-O output.
// Block: 128 q-rows x head x KV-half. Wave owns 32 q-cols. Grid (64, H, 2).
// [layouts HW-verified R6/R7]
// ---------------------------------------------------------------------------
__global__ __launch_bounds__(256, 2) void attn_mfma(
    const short* __restrict__ qb, const short* __restrict__ kb,
    const short* __restrict__ vb, short* __restrict__ opart,
    float* __restrict__ mlbuf)
{
    __shared__ short Ks[64][132];
    __shared__ short Vt[128][68];
    __shared__ short Ps[128][68];
    int tid = threadIdx.x;
    int w = tid >> 6, lane = tid & 63;
    int l31 = lane & 31, hi = lane >> 5;
    int blk = blockIdx.x, h = blockIdx.y, half = blockIdx.z;
    int b = blk >> 4;                       // 16 q-tiles of 128 per batch
    size_t qrow0 = (size_t)blk * 128;
    size_t sbase = (size_t)b * SEQ + (size_t)half * (SEQ / 2);

    int sK = tid >> 2, cK = tid & 3;          // K staging: row, 32-col chunk
    int sV = (tid & 15) * 4, dV = tid >> 4;   // V staging: 4 rows, 8-col chunk

    // ---- prefetch KV tile 0 into registers
    short8 kreg[4], vreg[4];
    {
        const short* ksrc = kb + (sbase + sK) * KVE + h * 128 + cK * 32;
#pragma unroll
        for (int j = 0; j < 4; j++) kreg[j] = *(const short8*)(ksrc + j * 8);
        const short* vsrc = vb + (sbase + sV) * KVE + h * 128 + dV * 8;
#pragma unroll
        for (int j = 0; j < 4; j++) vreg[j] = *(const short8*)(vsrc + j * KVE);
    }

    // ---- Q^T B-frags straight from global: head-pair sum, fold 1/128
    short8 qfrag[8];
    {
        const short* src = qb + (qrow0 + w * 32 + l31) * E + h * 256 + hi * 8;
#pragma unroll
        for (int j = 0; j < 8; j++) {
            short8 a  = *(const short8*)(src + j * 16);
            short8 b2 = *(const short8*)(src + j * 16 + 128);
            short8 o;
#pragma unroll
            for (int e = 0; e < 8; e++)
                o[e] = f2bf((bf2f(a[e]) + bf2f(b2[e])) * (1.0f / 128.0f));
            qfrag[j] = o;
        }
    }

    floatx16 oacc[4];
#pragma unroll
    for (int dt = 0; dt < 4; dt++)
#pragma unroll
        for (int r = 0; r < 16; r++) oacc[dt][r] = 0.f;
    float m_s = -1e30f, l_s = 0.f;

    for (int st = 0; st < SEQ / 128; st++) {
        __syncthreads();   // prior readers of Ks/Vt done
        // commit prefetched K tile
#pragma unroll
        for (int j = 0; j < 4; j++)
            *(short8*)&Ks[sK][cK * 32 + j * 8] = kreg[j];
        // commit prefetched V tile (transposed)
#pragma unroll
        for (int i = 0; i < 8; i++) {
            short4v vv = { vreg[0][i], vreg[1][i], vreg[2][i], vreg[3][i] };
            *(short4v*)&Vt[dV * 8 + i][sV] = vv;
        }
        // issue next tile's global loads
        if (st + 1 < SEQ / 128) {
            size_t srow0 = sbase + (size_t)(st + 1) * 64;
            const short* ksrc = kb + (srow0 + sK) * KVE + h * 128 + cK * 32;
#pragma unroll
            for (int j = 0; j < 4; j++) kreg[j] = *(const short8*)(ksrc + j * 8);
            const short* vsrc = vb + (srow0 + sV) * KVE + h * 128 + dV * 8;
#pragma unroll
            for (int j = 0; j < 4; j++) vreg[j] = *(const short8*)(vsrc + j * KVE);
        }
        __syncthreads();
        // S^T = K * Q^T: two 32x32 tiles (keys 0-31, 32-63) x 32 q-cols
        floatx16 sc0, sc1;
#pragma unroll
        for (int r = 0; r < 16; r++) { sc0[r] = 0.f; sc1[r] = 0.f; }
#pragma unroll
        for (int j = 0; j < 8; j++) {
            short8 kf0 = *(const short8*)&Ks[l31][j * 16 + hi * 8];
            short8 kf1 = *(const short8*)&Ks[32 + l31][j * 16 + hi * 8];
            sc0 = __builtin_amdgcn_mfma_f32_32x32x16_bf16(kf0, qfrag[j], sc0, 0, 0, 0);
            sc1 = __builtin_amdgcn_mfma_f32_32x32x16_bf16(kf1, qfrag[j], sc1, 0, 0, 0);
        }
        // online softmax: lane + lane^32 together hold all 64 keys for this q
        float mx = sc0[0];
#pragma unroll
        for (int r = 0; r < 16; r++) { mx = fmaxf(mx, sc0[r]); mx = fmaxf(mx, sc1[r]); }
        mx = fmaxf(mx, __shfl_xor(mx, 32));
        float nm = fmaxf(m_s, mx);
        float alpha = __expf(m_s - nm);
        m_s = nm;
        float rs = 0.f;
#pragma unroll
        for (int r = 0; r < 16; r++) {
            float p0 = __expf(sc0[r] - nm); sc0[r] = p0; rs += p0;
            float p1 = __expf(sc1[r] - nm); sc1[r] = p1; rs += p1;
        }
        rs += __shfl_xor(rs, 32);
        l_s = l_s * alpha + rs;
        // P -> LDS: regs c*4..c*4+3 are consecutive keys 8c+4hi(+t*32)
        int qrow = w * 32 + l31;
#pragma unroll
        for (int c = 0; c < 4; c++) {
            short4v p0 = { f2bf(sc0[c * 4]), f2bf(sc0[c * 4 + 1]),
                           f2bf(sc0[c * 4 + 2]), f2bf(sc0[c * 4 + 3]) };
            *(short4v*)&Ps[qrow][c * 8 + hi * 4] = p0;
            short4v p1 = { f2bf(sc1[c * 4]), f2bf(sc1[c * 4 + 1]),
                           f2bf(sc1[c * 4 + 2]), f2bf(sc1[c * 4 + 3]) };
            *(short4v*)&Ps[qrow][32 + c * 8 + hi * 4] = p1;
        }
        // rescale O^T
#pragma unroll
        for (int dt = 0; dt < 4; dt++)
#pragma unroll
            for (int r = 0; r < 16; r++) oacc[dt][r] *= alpha;
        // PV: O^T = V^T * P^T (A = Vt frag, B = P^T frag; same-wave LDS RAW)
        short8 pb[4];
#pragma unroll
        for (int j = 0; j < 4; j++)
            pb[j] = *(const short8*)&Ps[qrow][j * 16 + hi * 8];
#pragma unroll
        for (int dt = 0; dt < 4; dt++)
#pragma unroll
            for (int j = 0; j < 4; j++) {
                short8 vf = *(const short8*)&Vt[dt * 32 + l31][j * 16 + hi * 8];
                oacc[dt] = __builtin_amdgcn_mfma_f32_32x32x16_bf16(vf, pb[j], oacc[dt], 0, 0, 0);
            }
    }
    // epilogue: normalized partial O (bf16) + (m,l)
    {
        float inv = 1.0f / l_s;
        size_t grow = qrow0 + w * 32 + l31;
        short* dst = opart + ((size_t)half * ROWS + grow) * KVE + h * 128;
#pragma unroll
        for (int dt = 0; dt < 4; dt++)
#pragma unroll
            for (int c = 0; c < 4; c++) {
                short4v o4 = { f2bf(oacc[dt][c * 4] * inv),
                               f2bf(oacc[dt][c * 4 + 1] * inv),
                               f2bf(oacc[dt][c * 4 + 2] * inv),
                               f2bf(oacc[dt][c * 4 + 3] * inv) };
                *(short4v*)(dst + dt * 32 + c * 8 + hi * 4) = o4;
            }
        if (hi == 0) {
            float* ml = mlbuf + (((size_t)half * ROWS + grow) * H + h) * 2;
            ml[0] = m_s;
            ml[1] = l_s;
        }
    }
}

// ---------------------------------------------------------------------------
// Partial combine (bf16 partials) + LayerNorm + RMSNorm + int8 quant,
// wave-per-row. Block = 4 waves = 4 rows, grid ROWS/4.
// ---------------------------------------------------------------------------
__global__ __launch_bounds__(256) void ln_combine_kernel(
    const short* __restrict__ opart, const float* __restrict__ mlbuf,
    const float* __restrict__ gamma, const float* __restrict__ beta,
    int8_t* __restrict__ xq, float* __restrict__ dqv)
{
    int lane = threadIdx.x & 63, wv = threadIdx.x >> 6;
    int row = blockIdx.x * 4 + wv;
    float4 y[2];
    float s = 0.f, ss = 0.f;
#pragma unroll
    for (int j = 0; j < 2; j++) {
        int col = lane * 4 + j * 256;
        int h = j * 2 + (lane >> 5);
        const float* ml0 = mlbuf + ((size_t)row * H + h) * 2;
        const float* ml1 = mlbuf + (((size_t)ROWS + row) * H + h) * 2;
        float m1 = ml0[0], l1v = ml0[1], m2 = ml1[0], l2v = ml1[1];
        float M = fmaxf(m1, m2);
        float w1 = l1v * __expf(m1 - M), w2 = l2v * __expf(m2 - M);
        float winv = 1.0f / (w1 + w2);
        w1 *= winv; w2 *= winv;
        short4v o1 = *(const short4v*)(opart + (size_t)row * KVE + col);
        short4v o2 = *(const short4v*)(opart + ((size_t)ROWS + row) * KVE + col);
        float4 vv = { bf2f(o1.x) * w1 + bf2f(o2.x) * w2,
                      bf2f(o1.y) * w1 + bf2f(o2.y) * w2,
                      bf2f(o1.z) * w1 + bf2f(o2.z) * w2,
                      bf2f(o1.w) * w1 + bf2f(o2.w) * w2 };
        y[j] = vv;
        s += vv.x + vv.y + vv.z + vv.w;
        ss += vv.x * vv.x + vv.y * vv.y + vv.z * vv.z + vv.w * vv.w;
    }
#pragma unroll
    for (int o = 32; o; o >>= 1) { s += __shfl_xor(s, o); ss += __shfl_xor(ss, o); }
    float mu = s * (1.0f / KVE);
    float var = fmaxf(ss * (1.0f / KVE) - mu * mu, 0.0f);
    float inv = rsqrtf(var + 1e-5f);
    float sy = 0.f, am = 0.f;
#pragma unroll
    for (int j = 0; j < 2; j++) {
        int col = lane * 4 + j * 256;
        float4 g = *(const float4*)(gamma + col);
        float4 be = *(const float4*)(beta + col);
        y[j].x = (y[j].x - mu) * inv * g.x + be.x;
        y[j].y = (y[j].y - mu) * inv * g.y + be.y;
        y[j].z = (y[j].z - mu) * inv * g.z + be.z;
        y[j].w = (y[j].w - mu) * inv * g.w + be.w;
        sy += y[j].x * y[j].x + y[j].y * y[j].y + y[j].z * y[j].z + y[j].w * y[j].w;
        am = fmaxf(am, fmaxf(fmaxf(fabsf(y[j].x), fabsf(y[j].y)),
                             fmaxf(fabsf(y[j].z), fabsf(y[j].w))));
    }
#pragma unroll
    for (int o = 32; o; o >>= 1) { sy += __shfl_xor(sy, o); am = fmaxf(am, __shfl_xor(am, o)); }
    float rms = rsqrtf(sy * (1.0f / KVE) + 1e-6f);
    float cl = fmaxf(am * rms, 1e-5f);
    float kf = rms * (127.0f / cl);
#pragma unroll
    for (int j = 0; j < 2; j++) {
        int col = lane * 4 + j * 256;
        int q0 = max(-128, min(127, (int)rintf(y[j].x * kf)));
        int q1 = max(-128, min(127, (int)rintf(y[j].y * kf)));
        int q2 = max(-128, min(127, (int)rintf(y[j].z * kf)));
        int q3 = max(-128, min(127, (int)rintf(y[j].w * kf)));
        uint32_t pk = (uint32_t)(q0 & 0xff) | ((uint32_t)(q1 & 0xff) << 8) |
                      ((uint32_t)(q2 & 0xff) << 16) | ((uint32_t)(q3 & 0xff) << 24);
        *(uint32_t*)(xq + (size_t)row * KVE + col) = pk;
    }
    if (!lane) dqv[row] = cl * (1.0f / 127.0f);
}

// ---------------------------------------------------------------------------
extern "C" void kernel_launch(void* const* d_in, const int* in_sizes, int n_in,
                              void* d_out, int out_size, void* d_ws, size_t ws_size,
                              hipStream_t stream)
{
    const float* query = (const float*)d_in[0];
    const float* key   = (const float*)d_in[1];
    const float* value = (const float*)d_in[2];
    const float* q_w   = (const float*)d_in[3];
    const float* k_w   = (const float*)d_in[4];
    const float* v_w   = (const float*)d_in[5];
    const float* out_w = (const float*)d_in[6];
    const float* ln_g  = (const float*)d_in[7];
    const float* ln_b  = (const float*)d_in[8];
    float* out = (float*)d_out;

    // workspace carve (xq slice 2 aliases opart: dead before attn writes it)
    char* p = (char*)d_ws;
    float* stats = (float*)p;  p += 256;
    int8_t* wq_q = (int8_t*)p; p += (size_t)1024 * 1024;
    int8_t* wq_k = (int8_t*)p; p += (size_t)512 * 1024;
    int8_t* wq_v = (int8_t*)p; p += (size_t)512 * 1024;
    int8_t* wq_o = (int8_t*)p; p += (size_t)1024 * 512;
    int8_t* xq01 = (int8_t*)p; p += (size_t)2 * ROWS * E;
    float* dqv  = (float*)p;   p += (size_t)3 * ROWS * 4;
    short* qb   = (short*)p;   p += (size_t)ROWS * E * 2;
    short* kb   = (short*)p;   p += (size_t)ROWS * KVE * 2;
    short* vb   = (short*)p;   p += (size_t)ROWS * KVE * 2;
    short* opart = (short*)p;  p += (size_t)2 * ROWS * KVE * 2;
    float* mlbuf = (float*)p;  p += (size_t)2 * ROWS * H * 2 * 4;
    int8_t* xq2 = (int8_t*)opart;  // alias: 8 MB needed <= 16 MB, dead pre-attn
    if ((size_t)(p - (char*)d_ws) > ws_size) return;

    dim3 blk(256);
    hipMemsetAsync(stats, 0, 256, stream);
    pre_kernel<<<dim3(256 + 3 * ROWS / 4), blk, 0, stream>>>(query, key, value,
        q_w, k_w, v_w, out_w, xq01, xq2, dqv, stats);
    wquant_kernel<<<dim3(64, 4), blk, 0, stream>>>(q_w, k_w, v_w, out_w,
        1024 * 1024, 512 * 1024, 512 * 1024, 1024 * 512, stats, wq_q, wq_k, wq_v, wq_o);

    gemm_qkv<<<dim3(1024), blk, 0, stream>>>(xq01, xq2, wq_q, wq_k, wq_v,
        dqv, stats, qb, kb, vb);

    attn_mfma<<<dim3(ROWS / 128, H, 2), blk, 0, stream>>>(qb, kb, vb, opart, mlbuf);

    ln_combine_kernel<<<dim3(ROWS / 4), blk, 0, stream>>>(opart, mlbuf,
        ln_g, ln_b, xq01, dqv);
    gemm_out<<<dim3(8, 64), blk, 0, stream>>>(xq01, wq_o, dqv, stats, out);
}